// Round 1
// baseline (796.725 us; speedup 1.0000x reference)
//
#include <hip/hip_runtime.h>
#include <hip/hip_bf16.h>

// GCN: 3x (X@W -> scatter-add over edges -> +b -> relu) -> mean-pool -> MLP head
// fp32 throughout, correctness-first baseline.

static inline int divUp(int a, int b) { return (a + b - 1) / b; }

__device__ __forceinline__ void atomAddF(float* p, float v) {
    unsafeAtomicAdd(p, v);  // HW global_atomic_add_f32 on gfx950
}

// ---------------- GEMM: out[N,64] = X[N,K] @ W[K,64] ----------------
// Block tile 64 rows x 64 cols, 256 threads (16x16), 4x4 register tile.
// W (up to 128x64 = 32KB) staged fully in LDS; A staged in 32-k chunks.
__global__ __launch_bounds__(256) void gemm64(const float* __restrict__ X,
                                              const float* __restrict__ W,
                                              float* __restrict__ out,
                                              int Nrows, int K) {
    __shared__ float As[32][68];      // [k][m], padded stride 68 (16B-aligned rows)
    __shared__ float Bs[128 * 64];    // full W, [k][n] flat

    const int tid = threadIdx.x;
    const int tx = tid & 15;          // col group: cols tx*4..tx*4+3
    const int ty = tid >> 4;          // row group: rows ty*4..ty*4+3
    const int m0 = blockIdx.x * 64;

    // Stage all of W into LDS (K*64 floats, K in {64,128})
    const int wElems = K * 64;
    for (int idx = tid * 4; idx < wElems; idx += 256 * 4) {
        *(float4*)(&Bs[idx]) = *(const float4*)(W + idx);
    }

    float acc[4][4];
#pragma unroll
    for (int i = 0; i < 4; ++i)
#pragma unroll
        for (int j = 0; j < 4; ++j) acc[i][j] = 0.f;

    for (int k0 = 0; k0 < K; k0 += 32) {
        __syncthreads();  // protect As reuse (and cover Bs load on first iter)
        // Stage A tile: 64 rows x 32 k, transposed into As[k][m]
        for (int f = tid; f < 512; f += 256) {
            int row = f >> 3;          // 0..63
            int kk = (f & 7) * 4;      // 0,4,...,28
            int grow = m0 + row;
            float4 a4 = make_float4(0.f, 0.f, 0.f, 0.f);
            if (grow < Nrows)
                a4 = *(const float4*)(X + (size_t)grow * K + k0 + kk);
            As[kk + 0][row] = a4.x;
            As[kk + 1][row] = a4.y;
            As[kk + 2][row] = a4.z;
            As[kk + 3][row] = a4.w;
        }
        __syncthreads();
#pragma unroll
        for (int k = 0; k < 32; ++k) {
            float4 a4 = *(const float4*)(&As[k][ty * 4]);
            float4 b4 = *(const float4*)(&Bs[(k0 + k) * 64 + tx * 4]);
            float a[4] = {a4.x, a4.y, a4.z, a4.w};
            float b[4] = {b4.x, b4.y, b4.z, b4.w};
#pragma unroll
            for (int i = 0; i < 4; ++i)
#pragma unroll
                for (int j = 0; j < 4; ++j) acc[i][j] += a[i] * b[j];
        }
    }

#pragma unroll
    for (int i = 0; i < 4; ++i) {
        int row = m0 + ty * 4 + i;
        if (row < Nrows) {
            float4 o = make_float4(acc[i][0], acc[i][1], acc[i][2], acc[i][3]);
            *(float4*)(out + (size_t)row * 64 + tx * 4) = o;
        }
    }
}

// ---------------- Edge scatter: agg[rows[e]] += support[cols[e]] ----------------
// One lane per (edge, col). A 64-lane wave covers exactly one edge's 64 cols.
__global__ __launch_bounds__(256) void scatter_add(const float* __restrict__ support,
                                                   const int* __restrict__ rows,
                                                   const int* __restrict__ cols,
                                                   float* __restrict__ agg,
                                                   long total) {
    long stride = (long)gridDim.x * blockDim.x;
    for (long i = (long)blockIdx.x * blockDim.x + threadIdx.x; i < total; i += stride) {
        int e = (int)(i >> 6);
        int c = (int)(i & 63);
        int src = cols[e];
        int dst = rows[e];
        atomAddF(&agg[(size_t)dst * 64 + c], support[(size_t)src * 64 + c]);
    }
}

// ---------------- bias + optional relu, in place over [N,64] ----------------
__global__ __launch_bounds__(256) void bias_act(float* __restrict__ x,
                                                const float* __restrict__ b,
                                                long total, int doRelu) {
    long stride = (long)gridDim.x * blockDim.x;
    for (long i = (long)blockIdx.x * blockDim.x + threadIdx.x; i < total; i += stride) {
        int h = (int)(i & 63);
        float v = x[i] + b[h];
        if (doRelu) v = fmaxf(v, 0.f);
        x[i] = v;
    }
}

// ---------------- mean-pool: sums[batch[n]] += x[n]; counts[batch[n]] += 1 ----------------
__global__ __launch_bounds__(256) void pool_sum(const float* __restrict__ x,
                                                const int* __restrict__ batch,
                                                float* __restrict__ sums,
                                                long total) {
    long stride = (long)gridDim.x * blockDim.x;
    for (long i = (long)blockIdx.x * blockDim.x + threadIdx.x; i < total; i += stride) {
        int n = (int)(i >> 6);
        int h = (int)(i & 63);
        atomAddF(&sums[(size_t)batch[n] * 64 + h], x[i]);
    }
}

__global__ __launch_bounds__(256) void pool_count(const int* __restrict__ batch,
                                                  float* __restrict__ counts, int Nn) {
    int stride = gridDim.x * blockDim.x;
    for (int n = blockIdx.x * blockDim.x + threadIdx.x; n < Nn; n += stride) {
        atomAddF(&counts[batch[n]], 1.0f);
    }
}

// ---------------- MLP head: one thread per graph ----------------
__global__ __launch_bounds__(256) void head_kernel(const float* __restrict__ sums,
                                                   const float* __restrict__ counts,
                                                   const float* __restrict__ dw1,
                                                   const float* __restrict__ db1,
                                                   const float* __restrict__ dw2,
                                                   const float* __restrict__ db2,
                                                   const float* __restrict__ dw3,
                                                   const float* __restrict__ db3,
                                                   float* __restrict__ out, int G) {
    int g = blockIdx.x * blockDim.x + threadIdx.x;
    if (g >= G) return;
    float inv = 1.0f / fmaxf(counts[g], 1.0f);

    float m[64];
#pragma unroll
    for (int k = 0; k < 64; ++k) m[k] = sums[(size_t)g * 64 + k] * inv;

    float h1[16];
#pragma unroll
    for (int j = 0; j < 16; ++j) h1[j] = db1[j];
    for (int k = 0; k < 64; ++k) {
        float mv = m[k];
#pragma unroll
        for (int j = 0; j < 16; ++j) h1[j] += mv * dw1[k * 16 + j];
    }
#pragma unroll
    for (int j = 0; j < 16; ++j) h1[j] = fmaxf(h1[j], 0.f);

    float h2[8];
#pragma unroll
    for (int j = 0; j < 8; ++j) h2[j] = db2[j];
#pragma unroll
    for (int k = 0; k < 16; ++k) {
        float hv = h1[k];
#pragma unroll
        for (int j = 0; j < 8; ++j) h2[j] += hv * dw2[k * 8 + j];
    }
#pragma unroll
    for (int j = 0; j < 8; ++j) h2[j] = fmaxf(h2[j], 0.f);

    float z = db3[0];
#pragma unroll
    for (int k = 0; k < 8; ++k) z += h2[k] * dw3[k];
    out[g] = 1.0f / (1.0f + expf(-z));
}

extern "C" void kernel_launch(void* const* d_in, const int* in_sizes, int n_in,
                              void* d_out, int out_size, void* d_ws, size_t ws_size,
                              hipStream_t stream) {
    const float* feat = (const float*)d_in[0];
    const int* eidx   = (const int*)d_in[1];
    const int* batch  = (const int*)d_in[2];
    const float* w1 = (const float*)d_in[3];
    const float* b1 = (const float*)d_in[4];
    const float* w2 = (const float*)d_in[5];
    const float* b2 = (const float*)d_in[6];
    const float* w3 = (const float*)d_in[7];
    const float* b3 = (const float*)d_in[8];
    const float* dw1 = (const float*)d_in[9];
    const float* db1 = (const float*)d_in[10];
    const float* dw2 = (const float*)d_in[11];
    const float* db2 = (const float*)d_in[12];
    const float* dw3 = (const float*)d_in[13];
    const float* db3 = (const float*)d_in[14];

    const int H = in_sizes[4];              // 64
    const int F = in_sizes[3] / H;          // 128
    const int Nn = in_sizes[0] / F;         // 100000
    const int E = in_sizes[1] / 2;          // 800000
    const int G = out_size;                 // 512

    const int* rows = eidx;
    const int* cols = eidx + E;

    float* bufA = (float*)d_ws;                         // support buffer
    float* bufB = bufA + (size_t)Nn * H;                // agg / x buffer
    float* sums = bufB + (size_t)Nn * H;                // [G,64]
    float* counts = sums + (size_t)G * H;               // [G]

    dim3 blk(256);
    const int gemmGrid = divUp(Nn, 64);
    const long totNH = (long)Nn * 64;
    const long totE = (long)E * 64;
    const size_t nhBytes = (size_t)totNH * sizeof(float);

    // ---- layer 1 ----
    gemm64<<<gemmGrid, blk, 0, stream>>>(feat, w1, bufA, Nn, F);
    hipMemsetAsync(bufB, 0, nhBytes, stream);
    scatter_add<<<4096, blk, 0, stream>>>(bufA, rows, cols, bufB, totE);
    bias_act<<<2048, blk, 0, stream>>>(bufB, b1, totNH, 1);

    // ---- layer 2 ----
    gemm64<<<gemmGrid, blk, 0, stream>>>(bufB, w2, bufA, Nn, H);
    hipMemsetAsync(bufB, 0, nhBytes, stream);
    scatter_add<<<4096, blk, 0, stream>>>(bufA, rows, cols, bufB, totE);
    bias_act<<<2048, blk, 0, stream>>>(bufB, b2, totNH, 1);

    // ---- layer 3 (no relu) ----
    gemm64<<<gemmGrid, blk, 0, stream>>>(bufB, w3, bufA, Nn, H);
    hipMemsetAsync(bufB, 0, nhBytes, stream);
    scatter_add<<<4096, blk, 0, stream>>>(bufA, rows, cols, bufB, totE);
    bias_act<<<2048, blk, 0, stream>>>(bufB, b3, totNH, 0);

    // ---- mean pool ----
    hipMemsetAsync(sums, 0, (size_t)G * H * sizeof(float), stream);
    hipMemsetAsync(counts, 0, (size_t)G * sizeof(float), stream);
    pool_sum<<<2048, blk, 0, stream>>>(bufB, batch, sums, totNH);
    pool_count<<<256, blk, 0, stream>>>(batch, counts, Nn);

    // ---- head ----
    head_kernel<<<divUp(G, 256), blk, 0, stream>>>(sums, counts, dw1, db1, dw2, db2,
                                                   dw3, db3, (float*)d_out, G);
}

// Round 2
// 549.952 us; speedup vs baseline: 1.4487x; 1.4487x over previous
//
#include <hip/hip_runtime.h>
#include <hip/hip_bf16.h>

// GCN: 3x (X@W -> CSR-gather aggregation + bias (+relu)) -> fused mean-pool -> MLP head
// CSR built on-device per launch (deterministic work; fp sum order within a node may
// vary via atomic fill, error ~1e-6 << threshold).

static inline int divUp(int a, int b) { return (a + b - 1) / b; }

__device__ __forceinline__ void atomAddF(float* p, float v) {
    unsafeAtomicAdd(p, v);  // HW global_atomic_add_f32 on gfx950
}

// ---------------- GEMM: out[N,64] = X[N,K] @ W[K,64] ----------------
__global__ __launch_bounds__(256) void gemm64(const float* __restrict__ X,
                                              const float* __restrict__ W,
                                              float* __restrict__ out,
                                              int Nrows, int K) {
    __shared__ float As[32][68];
    __shared__ float Bs[128 * 64];

    const int tid = threadIdx.x;
    const int tx = tid & 15;
    const int ty = tid >> 4;
    const int m0 = blockIdx.x * 64;

    const int wElems = K * 64;
    for (int idx = tid * 4; idx < wElems; idx += 256 * 4) {
        *(float4*)(&Bs[idx]) = *(const float4*)(W + idx);
    }

    float acc[4][4];
#pragma unroll
    for (int i = 0; i < 4; ++i)
#pragma unroll
        for (int j = 0; j < 4; ++j) acc[i][j] = 0.f;

    for (int k0 = 0; k0 < K; k0 += 32) {
        __syncthreads();
        for (int f = tid; f < 512; f += 256) {
            int row = f >> 3;
            int kk = (f & 7) * 4;
            int grow = m0 + row;
            float4 a4 = make_float4(0.f, 0.f, 0.f, 0.f);
            if (grow < Nrows)
                a4 = *(const float4*)(X + (size_t)grow * K + k0 + kk);
            As[kk + 0][row] = a4.x;
            As[kk + 1][row] = a4.y;
            As[kk + 2][row] = a4.z;
            As[kk + 3][row] = a4.w;
        }
        __syncthreads();
#pragma unroll
        for (int k = 0; k < 32; ++k) {
            float4 a4 = *(const float4*)(&As[k][ty * 4]);
            float4 b4 = *(const float4*)(&Bs[(k0 + k) * 64 + tx * 4]);
            float a[4] = {a4.x, a4.y, a4.z, a4.w};
            float b[4] = {b4.x, b4.y, b4.z, b4.w};
#pragma unroll
            for (int i = 0; i < 4; ++i)
#pragma unroll
                for (int j = 0; j < 4; ++j) acc[i][j] += a[i] * b[j];
        }
    }

#pragma unroll
    for (int i = 0; i < 4; ++i) {
        int row = m0 + ty * 4 + i;
        if (row < Nrows) {
            float4 o = make_float4(acc[i][0], acc[i][1], acc[i][2], acc[i][3]);
            *(float4*)(out + (size_t)row * 64 + tx * 4) = o;
        }
    }
}

// ---------------- CSR build ----------------
__global__ __launch_bounds__(256) void hist_kernel(const int* __restrict__ rows,
                                                   int* __restrict__ deg, int E) {
    int stride = gridDim.x * blockDim.x;
    for (int e = blockIdx.x * blockDim.x + threadIdx.x; e < E; e += stride)
        atomicAdd(&deg[rows[e]], 1);
}

// Block-local exclusive scan over chunks of 1024 (256 thr x 4 elems).
__global__ __launch_bounds__(256) void scanA(const int* __restrict__ deg,
                                             int* __restrict__ offsets,
                                             int* __restrict__ blockSums, int Nn) {
    __shared__ int wsum[4];
    const int tid = threadIdx.x;
    const int lane = tid & 63;
    const int wid = tid >> 6;
    const int i0 = blockIdx.x * 1024 + tid * 4;

    int v[4];
#pragma unroll
    for (int j = 0; j < 4; ++j) v[j] = (i0 + j < Nn) ? deg[i0 + j] : 0;
    int t = v[0] + v[1] + v[2] + v[3];

    int x = t;
#pragma unroll
    for (int d = 1; d < 64; d <<= 1) {
        int y = __shfl_up(x, d, 64);
        if (lane >= d) x += y;
    }
    if (lane == 63) wsum[wid] = x;
    __syncthreads();
    int waveExcl = 0;
#pragma unroll
    for (int w = 0; w < 4; ++w)
        if (w < wid) waveExcl += wsum[w];

    int e = waveExcl + (x - t);  // block-local exclusive prefix
#pragma unroll
    for (int j = 0; j < 4; ++j) {
        if (i0 + j < Nn) offsets[i0 + j] = e;
        e += v[j];
    }
    if (tid == 0) blockSums[blockIdx.x] = wsum[0] + wsum[1] + wsum[2] + wsum[3];
}

__global__ void scanB(int* __restrict__ blockSums, int* __restrict__ blockOffs, int nb) {
    if (threadIdx.x == 0 && blockIdx.x == 0) {
        int run = 0;
        for (int b = 0; b < nb; ++b) {
            blockOffs[b] = run;
            run += blockSums[b];
        }
    }
}

__global__ __launch_bounds__(256) void scanC(int* __restrict__ offsets,
                                             const int* __restrict__ blockOffs,
                                             int* __restrict__ fillPos, int Nn) {
    const int i0 = blockIdx.x * 1024 + threadIdx.x * 4;
    const int add = blockOffs[blockIdx.x];
#pragma unroll
    for (int j = 0; j < 4; ++j) {
        if (i0 + j < Nn) {
            int o = offsets[i0 + j] + add;
            offsets[i0 + j] = o;
            fillPos[i0 + j] = o;
        }
    }
}

__global__ __launch_bounds__(256) void fill_kernel(const int* __restrict__ rows,
                                                   const int* __restrict__ cols,
                                                   int* __restrict__ fillPos,
                                                   int* __restrict__ csrSrc, int E) {
    int stride = gridDim.x * blockDim.x;
    for (int e = blockIdx.x * blockDim.x + threadIdx.x; e < E; e += stride) {
        int pos = atomicAdd(&fillPos[rows[e]], 1);
        csrSrc[pos] = cols[e];
    }
}

// ---------------- CSR aggregation: out[n] = sum_{e in csr(n)} support[src(e)] + b ----------------
// One wave (64 lanes) per node; lane = column.
__global__ __launch_bounds__(256) void agg_csr(const float* __restrict__ support,
                                               const int* __restrict__ offsets,
                                               const int* __restrict__ deg,
                                               const int* __restrict__ csrSrc,
                                               const float* __restrict__ bias,
                                               float* __restrict__ out,
                                               int Nn, int doRelu) {
    const int lane = threadIdx.x & 63;
    const int node = blockIdx.x * 4 + (threadIdx.x >> 6);
    if (node >= Nn) return;
    const int off = offsets[node];
    const int d = deg[node];
    float acc0 = 0.f, acc1 = 0.f;
    int i = 0;
    for (; i + 1 < d; i += 2) {
        int s0 = csrSrc[off + i];
        int s1 = csrSrc[off + i + 1];
        acc0 += support[(size_t)s0 * 64 + lane];
        acc1 += support[(size_t)s1 * 64 + lane];
    }
    if (i < d) acc0 += support[(size_t)csrSrc[off + i] * 64 + lane];
    float v = acc0 + acc1 + bias[lane];
    if (doRelu) v = fmaxf(v, 0.f);
    out[(size_t)node * 64 + lane] = v;
}

// Layer-3 aggregation fused with mean-pool accumulation (no x write-back).
__global__ __launch_bounds__(256) void agg_pool(const float* __restrict__ support,
                                                const int* __restrict__ offsets,
                                                const int* __restrict__ deg,
                                                const int* __restrict__ csrSrc,
                                                const float* __restrict__ bias,
                                                const int* __restrict__ batch,
                                                float* __restrict__ sums,
                                                float* __restrict__ counts, int Nn) {
    const int lane = threadIdx.x & 63;
    const int node = blockIdx.x * 4 + (threadIdx.x >> 6);
    if (node >= Nn) return;
    const int off = offsets[node];
    const int d = deg[node];
    float acc0 = 0.f, acc1 = 0.f;
    int i = 0;
    for (; i + 1 < d; i += 2) {
        int s0 = csrSrc[off + i];
        int s1 = csrSrc[off + i + 1];
        acc0 += support[(size_t)s0 * 64 + lane];
        acc1 += support[(size_t)s1 * 64 + lane];
    }
    if (i < d) acc0 += support[(size_t)csrSrc[off + i] * 64 + lane];
    float v = acc0 + acc1 + bias[lane];
    int g = batch[node];
    atomAddF(&sums[(size_t)g * 64 + lane], v);
    if (lane == 0) atomAddF(&counts[g], 1.0f);
}

// ---------------- fallback-path kernels (atomic scatter) ----------------
__global__ __launch_bounds__(256) void scatter_add(const float* __restrict__ support,
                                                   const int* __restrict__ rows,
                                                   const int* __restrict__ cols,
                                                   float* __restrict__ agg, long total) {
    long stride = (long)gridDim.x * blockDim.x;
    for (long i = (long)blockIdx.x * blockDim.x + threadIdx.x; i < total; i += stride) {
        int e = (int)(i >> 6);
        int c = (int)(i & 63);
        atomAddF(&agg[(size_t)rows[e] * 64 + c], support[(size_t)cols[e] * 64 + c]);
    }
}

__global__ __launch_bounds__(256) void bias_act(float* __restrict__ x,
                                                const float* __restrict__ b,
                                                long total, int doRelu) {
    long stride = (long)gridDim.x * blockDim.x;
    for (long i = (long)blockIdx.x * blockDim.x + threadIdx.x; i < total; i += stride) {
        int h = (int)(i & 63);
        float v = x[i] + b[h];
        if (doRelu) v = fmaxf(v, 0.f);
        x[i] = v;
    }
}

__global__ __launch_bounds__(256) void pool_sum(const float* __restrict__ x,
                                                const int* __restrict__ batch,
                                                float* __restrict__ sums, long total) {
    long stride = (long)gridDim.x * blockDim.x;
    for (long i = (long)blockIdx.x * blockDim.x + threadIdx.x; i < total; i += stride) {
        int n = (int)(i >> 6);
        int h = (int)(i & 63);
        atomAddF(&sums[(size_t)batch[n] * 64 + h], x[i]);
    }
}

__global__ __launch_bounds__(256) void pool_count(const int* __restrict__ batch,
                                                  float* __restrict__ counts, int Nn) {
    int stride = gridDim.x * blockDim.x;
    for (int n = blockIdx.x * blockDim.x + threadIdx.x; n < Nn; n += stride)
        atomAddF(&counts[batch[n]], 1.0f);
}

// ---------------- MLP head ----------------
__global__ __launch_bounds__(256) void head_kernel(const float* __restrict__ sums,
                                                   const float* __restrict__ counts,
                                                   const float* __restrict__ dw1,
                                                   const float* __restrict__ db1,
                                                   const float* __restrict__ dw2,
                                                   const float* __restrict__ db2,
                                                   const float* __restrict__ dw3,
                                                   const float* __restrict__ db3,
                                                   float* __restrict__ out, int G) {
    int g = blockIdx.x * blockDim.x + threadIdx.x;
    if (g >= G) return;
    float inv = 1.0f / fmaxf(counts[g], 1.0f);

    float m[64];
#pragma unroll
    for (int k = 0; k < 64; ++k) m[k] = sums[(size_t)g * 64 + k] * inv;

    float h1[16];
#pragma unroll
    for (int j = 0; j < 16; ++j) h1[j] = db1[j];
    for (int k = 0; k < 64; ++k) {
        float mv = m[k];
#pragma unroll
        for (int j = 0; j < 16; ++j) h1[j] += mv * dw1[k * 16 + j];
    }
#pragma unroll
    for (int j = 0; j < 16; ++j) h1[j] = fmaxf(h1[j], 0.f);

    float h2[8];
#pragma unroll
    for (int j = 0; j < 8; ++j) h2[j] = db2[j];
#pragma unroll
    for (int k = 0; k < 16; ++k) {
        float hv = h1[k];
#pragma unroll
        for (int j = 0; j < 8; ++j) h2[j] += hv * dw2[k * 8 + j];
    }
#pragma unroll
    for (int j = 0; j < 8; ++j) h2[j] = fmaxf(h2[j], 0.f);

    float z = db3[0];
#pragma unroll
    for (int k = 0; k < 8; ++k) z += h2[k] * dw3[k];
    out[g] = 1.0f / (1.0f + expf(-z));
}

extern "C" void kernel_launch(void* const* d_in, const int* in_sizes, int n_in,
                              void* d_out, int out_size, void* d_ws, size_t ws_size,
                              hipStream_t stream) {
    const float* feat = (const float*)d_in[0];
    const int* eidx   = (const int*)d_in[1];
    const int* batch  = (const int*)d_in[2];
    const float* w1 = (const float*)d_in[3];
    const float* b1 = (const float*)d_in[4];
    const float* w2 = (const float*)d_in[5];
    const float* b2 = (const float*)d_in[6];
    const float* w3 = (const float*)d_in[7];
    const float* b3 = (const float*)d_in[8];
    const float* dw1 = (const float*)d_in[9];
    const float* db1 = (const float*)d_in[10];
    const float* dw2 = (const float*)d_in[11];
    const float* db2 = (const float*)d_in[12];
    const float* dw3 = (const float*)d_in[13];
    const float* db3 = (const float*)d_in[14];

    const int H = in_sizes[4];              // 64
    const int F = in_sizes[3] / H;          // 128
    const int Nn = in_sizes[0] / F;         // 100000
    const int E = in_sizes[1] / 2;          // 800000
    const int G = out_size;                 // 512

    const int* rows = eidx;
    const int* cols = eidx + E;

    // workspace layout
    float* bufA = (float*)d_ws;
    float* bufB = bufA + (size_t)Nn * H;
    float* sums = bufB + (size_t)Nn * H;
    float* counts = sums + (size_t)G * H;
    int* deg = (int*)(counts + G);
    int* offsets = deg + Nn;
    int* fillPos = offsets + Nn;
    int* csrSrc = fillPos + Nn;
    int* blockSums = csrSrc + E;
    int* blockOffs = blockSums + 256;
    size_t needed = (size_t)((char*)(blockOffs + 256) - (char*)d_ws);

    dim3 blk(256);
    const int gemmGrid = divUp(Nn, 64);
    const long totNH = (long)Nn * 64;

    hipMemsetAsync(sums, 0, (size_t)G * H * sizeof(float), stream);
    hipMemsetAsync(counts, 0, (size_t)G * sizeof(float), stream);

    if (needed <= ws_size) {
        // ---- CSR build ----
        const int nb = divUp(Nn, 1024);
        hipMemsetAsync(deg, 0, (size_t)Nn * sizeof(int), stream);
        hist_kernel<<<2048, blk, 0, stream>>>(rows, deg, E);
        scanA<<<nb, blk, 0, stream>>>(deg, offsets, blockSums, Nn);
        scanB<<<1, 64, 0, stream>>>(blockSums, blockOffs, nb);
        scanC<<<nb, blk, 0, stream>>>(offsets, blockOffs, fillPos, Nn);
        fill_kernel<<<2048, blk, 0, stream>>>(rows, cols, fillPos, csrSrc, E);

        const int aggGrid = divUp(Nn, 4);
        // ---- layer 1 ----
        gemm64<<<gemmGrid, blk, 0, stream>>>(feat, w1, bufA, Nn, F);
        agg_csr<<<aggGrid, blk, 0, stream>>>(bufA, offsets, deg, csrSrc, b1, bufB, Nn, 1);
        // ---- layer 2 ----
        gemm64<<<gemmGrid, blk, 0, stream>>>(bufB, w2, bufA, Nn, H);
        agg_csr<<<aggGrid, blk, 0, stream>>>(bufA, offsets, deg, csrSrc, b2, bufB, Nn, 1);
        // ---- layer 3 + pool ----
        gemm64<<<gemmGrid, blk, 0, stream>>>(bufB, w3, bufA, Nn, H);
        agg_pool<<<aggGrid, blk, 0, stream>>>(bufA, offsets, deg, csrSrc, b3, batch,
                                              sums, counts, Nn);
    } else {
        // fallback: atomic scatter path
        const long totE = (long)E * 64;
        const size_t nhBytes = (size_t)totNH * sizeof(float);
        gemm64<<<gemmGrid, blk, 0, stream>>>(feat, w1, bufA, Nn, F);
        hipMemsetAsync(bufB, 0, nhBytes, stream);
        scatter_add<<<4096, blk, 0, stream>>>(bufA, rows, cols, bufB, totE);
        bias_act<<<2048, blk, 0, stream>>>(bufB, b1, totNH, 1);
        gemm64<<<gemmGrid, blk, 0, stream>>>(bufB, w2, bufA, Nn, H);
        hipMemsetAsync(bufB, 0, nhBytes, stream);
        scatter_add<<<4096, blk, 0, stream>>>(bufA, rows, cols, bufB, totE);
        bias_act<<<2048, blk, 0, stream>>>(bufB, b2, totNH, 1);
        gemm64<<<gemmGrid, blk, 0, stream>>>(bufB, w3, bufA, Nn, H);
        hipMemsetAsync(bufB, 0, nhBytes, stream);
        scatter_add<<<4096, blk, 0, stream>>>(bufA, rows, cols, bufB, totE);
        bias_act<<<2048, blk, 0, stream>>>(bufB, b3, totNH, 0);
        pool_sum<<<2048, blk, 0, stream>>>(bufB, batch, sums, totNH);
        pool_count<<<256, blk, 0, stream>>>(batch, counts, Nn);
    }

    // ---- head ----
    head_kernel<<<divUp(G, 256), blk, 0, stream>>>(sums, counts, dw1, db1, dw2, db2,
                                                   dw3, db3, (float*)d_out, G);
}

// Round 3
// 358.682 us; speedup vs baseline: 2.2213x; 1.5333x over previous
//
#include <hip/hip_runtime.h>
#include <hip/hip_bf16.h>

// GCN: 3x (X@W -> CSR-gather agg + bias (+relu)) -> segmented mean-pool -> MLP head
// CSR built on-device per launch. batch[] is sorted -> pool is a contiguous
// segmented reduction (no atomics).

static inline int divUp(int a, int b) { return (a + b - 1) / b; }

// ---------------- GEMM: out[N,64] = X[N,K] @ W[K,64] ----------------
__global__ __launch_bounds__(256) void gemm64(const float* __restrict__ X,
                                              const float* __restrict__ W,
                                              float* __restrict__ out,
                                              int Nrows, int K) {
    __shared__ float As[32][68];
    __shared__ float Bs[128 * 64];

    const int tid = threadIdx.x;
    const int tx = tid & 15;
    const int ty = tid >> 4;
    const int m0 = blockIdx.x * 64;

    const int wElems = K * 64;
    for (int idx = tid * 4; idx < wElems; idx += 256 * 4) {
        *(float4*)(&Bs[idx]) = *(const float4*)(W + idx);
    }

    float acc[4][4];
#pragma unroll
    for (int i = 0; i < 4; ++i)
#pragma unroll
        for (int j = 0; j < 4; ++j) acc[i][j] = 0.f;

    for (int k0 = 0; k0 < K; k0 += 32) {
        __syncthreads();
        for (int f = tid; f < 512; f += 256) {
            int row = f >> 3;
            int kk = (f & 7) * 4;
            int grow = m0 + row;
            float4 a4 = make_float4(0.f, 0.f, 0.f, 0.f);
            if (grow < Nrows)
                a4 = *(const float4*)(X + (size_t)grow * K + k0 + kk);
            As[kk + 0][row] = a4.x;
            As[kk + 1][row] = a4.y;
            As[kk + 2][row] = a4.z;
            As[kk + 3][row] = a4.w;
        }
        __syncthreads();
#pragma unroll
        for (int k = 0; k < 32; ++k) {
            float4 a4 = *(const float4*)(&As[k][ty * 4]);
            float4 b4 = *(const float4*)(&Bs[(k0 + k) * 64 + tx * 4]);
            float a[4] = {a4.x, a4.y, a4.z, a4.w};
            float b[4] = {b4.x, b4.y, b4.z, b4.w};
#pragma unroll
            for (int i = 0; i < 4; ++i)
#pragma unroll
                for (int j = 0; j < 4; ++j) acc[i][j] += a[i] * b[j];
        }
    }

#pragma unroll
    for (int i = 0; i < 4; ++i) {
        int row = m0 + ty * 4 + i;
        if (row < Nrows) {
            float4 o = make_float4(acc[i][0], acc[i][1], acc[i][2], acc[i][3]);
            *(float4*)(out + (size_t)row * 64 + tx * 4) = o;
        }
    }
}

// ---------------- CSR build ----------------
__global__ __launch_bounds__(256) void hist_kernel(const int* __restrict__ rows,
                                                   int* __restrict__ deg, int E) {
    int stride = gridDim.x * blockDim.x;
    for (int e = blockIdx.x * blockDim.x + threadIdx.x; e < E; e += stride)
        atomicAdd(&deg[rows[e]], 1);
}

__global__ __launch_bounds__(256) void scanA(const int* __restrict__ deg,
                                             int* __restrict__ offsets,
                                             int* __restrict__ blockSums, int Nn) {
    __shared__ int wsum[4];
    const int tid = threadIdx.x;
    const int lane = tid & 63;
    const int wid = tid >> 6;
    const int i0 = blockIdx.x * 1024 + tid * 4;

    int v[4];
#pragma unroll
    for (int j = 0; j < 4; ++j) v[j] = (i0 + j < Nn) ? deg[i0 + j] : 0;
    int t = v[0] + v[1] + v[2] + v[3];

    int x = t;
#pragma unroll
    for (int d = 1; d < 64; d <<= 1) {
        int y = __shfl_up(x, d, 64);
        if (lane >= d) x += y;
    }
    if (lane == 63) wsum[wid] = x;
    __syncthreads();
    int waveExcl = 0;
#pragma unroll
    for (int w = 0; w < 4; ++w)
        if (w < wid) waveExcl += wsum[w];

    int e = waveExcl + (x - t);
#pragma unroll
    for (int j = 0; j < 4; ++j) {
        if (i0 + j < Nn) offsets[i0 + j] = e;
        e += v[j];
    }
    if (tid == 0) blockSums[blockIdx.x] = wsum[0] + wsum[1] + wsum[2] + wsum[3];
}

__global__ void scanB(int* __restrict__ blockSums, int* __restrict__ blockOffs, int nb) {
    if (threadIdx.x == 0 && blockIdx.x == 0) {
        int run = 0;
        for (int b = 0; b < nb; ++b) {
            blockOffs[b] = run;
            run += blockSums[b];
        }
    }
}

__global__ __launch_bounds__(256) void scanC(int* __restrict__ offsets,
                                             const int* __restrict__ blockOffs,
                                             int* __restrict__ fillPos, int Nn) {
    const int i0 = blockIdx.x * 1024 + threadIdx.x * 4;
    const int add = blockOffs[blockIdx.x];
#pragma unroll
    for (int j = 0; j < 4; ++j) {
        if (i0 + j < Nn) {
            int o = offsets[i0 + j] + add;
            offsets[i0 + j] = o;
            fillPos[i0 + j] = o;
        }
    }
}

__global__ __launch_bounds__(256) void fill_kernel(const int* __restrict__ rows,
                                                   const int* __restrict__ cols,
                                                   int* __restrict__ fillPos,
                                                   int* __restrict__ csrSrc, int E) {
    int stride = gridDim.x * blockDim.x;
    for (int e = blockIdx.x * blockDim.x + threadIdx.x; e < E; e += stride) {
        int pos = atomicAdd(&fillPos[rows[e]], 1);
        csrSrc[pos] = cols[e];
    }
}

// ---------------- CSR aggregation ----------------
// One wave per node; 4 subgroups of 16 lanes, each subgroup takes every 4th
// edge with float4 loads (4 cache lines in flight / wave); cross-subgroup
// reduce via shfl_xor(16), shfl_xor(32).
__global__ __launch_bounds__(256) void agg_csr4(const float* __restrict__ support,
                                                const int* __restrict__ offsets,
                                                const int* __restrict__ deg,
                                                const int* __restrict__ csrSrc,
                                                const float* __restrict__ bias,
                                                float* __restrict__ out,
                                                int Nn, int doRelu) {
    const int lane = threadIdx.x & 63;
    const int node = blockIdx.x * 4 + (threadIdx.x >> 6);
    if (node >= Nn) return;
    const int off = offsets[node];
    const int d = deg[node];
    const int sub = lane >> 4;
    const int sl = lane & 15;

    float4 acc = make_float4(0.f, 0.f, 0.f, 0.f);
    for (int i = sub; i < d; i += 4) {
        int s = csrSrc[off + i];
        float4 v = *(const float4*)(support + (size_t)s * 64 + sl * 4);
        acc.x += v.x; acc.y += v.y; acc.z += v.z; acc.w += v.w;
    }
    acc.x += __shfl_xor(acc.x, 16); acc.y += __shfl_xor(acc.y, 16);
    acc.z += __shfl_xor(acc.z, 16); acc.w += __shfl_xor(acc.w, 16);
    acc.x += __shfl_xor(acc.x, 32); acc.y += __shfl_xor(acc.y, 32);
    acc.z += __shfl_xor(acc.z, 32); acc.w += __shfl_xor(acc.w, 32);

    if (sub == 0) {
        float4 b4 = *(const float4*)(bias + sl * 4);
        float4 o;
        o.x = acc.x + b4.x; o.y = acc.y + b4.y;
        o.z = acc.z + b4.z; o.w = acc.w + b4.w;
        if (doRelu) {
            o.x = fmaxf(o.x, 0.f); o.y = fmaxf(o.y, 0.f);
            o.z = fmaxf(o.z, 0.f); o.w = fmaxf(o.w, 0.f);
        }
        *(float4*)(out + (size_t)node * 64 + sl * 4) = o;
    }
}

// ---------------- graph bounds via binary search on sorted batch ----------------
__global__ __launch_bounds__(256) void graph_bounds(const int* __restrict__ batch,
                                                    int Nn, int* __restrict__ gstart,
                                                    int* __restrict__ gcnt, int G) {
    int g = blockIdx.x * blockDim.x + threadIdx.x;
    if (g >= G) return;
    // lower_bound(g)
    int lo = 0, hi = Nn;
    while (lo < hi) { int mid = (lo + hi) >> 1; if (batch[mid] < g) lo = mid + 1; else hi = mid; }
    int s = lo;
    // lower_bound(g+1)
    hi = Nn;
    while (lo < hi) { int mid = (lo + hi) >> 1; if (batch[mid] < g + 1) lo = mid + 1; else hi = mid; }
    gstart[g] = s;
    gcnt[g] = lo - s;
}

// ---------------- segmented mean pool: one block per graph ----------------
__global__ __launch_bounds__(256) void pool_seg(const float* __restrict__ x,
                                                const int* __restrict__ gstart,
                                                const int* __restrict__ gcnt,
                                                float* __restrict__ pooled) {
    __shared__ float red[4][64];
    const int g = blockIdx.x;
    const int lane = threadIdx.x & 63;
    const int wid = threadIdx.x >> 6;
    const int s = gstart[g];
    const int c = gcnt[g];

    float acc = 0.f;
    for (int i = s + wid; i < s + c; i += 4)
        acc += x[(size_t)i * 64 + lane];
    red[wid][lane] = acc;
    __syncthreads();
    if (wid == 0) {
        float v = red[0][lane] + red[1][lane] + red[2][lane] + red[3][lane];
        pooled[(size_t)g * 64 + lane] = v / fmaxf((float)c, 1.f);
    }
}

// ---------------- MLP head (input = pooled means) ----------------
__global__ __launch_bounds__(256) void head_kernel(const float* __restrict__ pooled,
                                                   const float* __restrict__ dw1,
                                                   const float* __restrict__ db1,
                                                   const float* __restrict__ dw2,
                                                   const float* __restrict__ db2,
                                                   const float* __restrict__ dw3,
                                                   const float* __restrict__ db3,
                                                   float* __restrict__ out, int G) {
    int g = blockIdx.x * blockDim.x + threadIdx.x;
    if (g >= G) return;

    float m[64];
#pragma unroll
    for (int k = 0; k < 64; ++k) m[k] = pooled[(size_t)g * 64 + k];

    float h1[16];
#pragma unroll
    for (int j = 0; j < 16; ++j) h1[j] = db1[j];
    for (int k = 0; k < 64; ++k) {
        float mv = m[k];
#pragma unroll
        for (int j = 0; j < 16; ++j) h1[j] += mv * dw1[k * 16 + j];
    }
#pragma unroll
    for (int j = 0; j < 16; ++j) h1[j] = fmaxf(h1[j], 0.f);

    float h2[8];
#pragma unroll
    for (int j = 0; j < 8; ++j) h2[j] = db2[j];
#pragma unroll
    for (int k = 0; k < 16; ++k) {
        float hv = h1[k];
#pragma unroll
        for (int j = 0; j < 8; ++j) h2[j] += hv * dw2[k * 8 + j];
    }
#pragma unroll
    for (int j = 0; j < 8; ++j) h2[j] = fmaxf(h2[j], 0.f);

    float z = db3[0];
#pragma unroll
    for (int k = 0; k < 8; ++k) z += h2[k] * dw3[k];
    out[g] = 1.0f / (1.0f + expf(-z));
}

extern "C" void kernel_launch(void* const* d_in, const int* in_sizes, int n_in,
                              void* d_out, int out_size, void* d_ws, size_t ws_size,
                              hipStream_t stream) {
    const float* feat = (const float*)d_in[0];
    const int* eidx   = (const int*)d_in[1];
    const int* batch  = (const int*)d_in[2];
    const float* w1 = (const float*)d_in[3];
    const float* b1 = (const float*)d_in[4];
    const float* w2 = (const float*)d_in[5];
    const float* b2 = (const float*)d_in[6];
    const float* w3 = (const float*)d_in[7];
    const float* b3 = (const float*)d_in[8];
    const float* dw1 = (const float*)d_in[9];
    const float* db1 = (const float*)d_in[10];
    const float* dw2 = (const float*)d_in[11];
    const float* db2 = (const float*)d_in[12];
    const float* dw3 = (const float*)d_in[13];
    const float* db3 = (const float*)d_in[14];

    const int H = in_sizes[4];              // 64
    const int F = in_sizes[3] / H;          // 128
    const int Nn = in_sizes[0] / F;         // 100000
    const int E = in_sizes[1] / 2;          // 800000
    const int G = out_size;                 // 512

    const int* rows = eidx;
    const int* cols = eidx + E;

    // workspace layout
    float* bufA = (float*)d_ws;                         // support [N,64]
    float* bufB = bufA + (size_t)Nn * H;                // x       [N,64]
    float* pooled = bufB + (size_t)Nn * H;              // [G,64]
    int* deg = (int*)(pooled + (size_t)G * H);
    int* offsets = deg + Nn;
    int* fillPos = offsets + Nn;
    int* csrSrc = fillPos + Nn;
    int* blockSums = csrSrc + E;
    int* blockOffs = blockSums + 256;
    int* gstart = blockOffs + 256;
    int* gcnt = gstart + G;

    dim3 blk(256);
    const int gemmGrid = divUp(Nn, 64);
    const int aggGrid = divUp(Nn, 4);
    const int nb = divUp(Nn, 1024);

    // ---- CSR build + graph bounds ----
    hipMemsetAsync(deg, 0, (size_t)Nn * sizeof(int), stream);
    hist_kernel<<<2048, blk, 0, stream>>>(rows, deg, E);
    scanA<<<nb, blk, 0, stream>>>(deg, offsets, blockSums, Nn);
    scanB<<<1, 64, 0, stream>>>(blockSums, blockOffs, nb);
    scanC<<<nb, blk, 0, stream>>>(offsets, blockOffs, fillPos, Nn);
    fill_kernel<<<2048, blk, 0, stream>>>(rows, cols, fillPos, csrSrc, E);
    graph_bounds<<<divUp(G, 256), blk, 0, stream>>>(batch, Nn, gstart, gcnt, G);

    // ---- layer 1 ----
    gemm64<<<gemmGrid, blk, 0, stream>>>(feat, w1, bufA, Nn, F);
    agg_csr4<<<aggGrid, blk, 0, stream>>>(bufA, offsets, deg, csrSrc, b1, bufB, Nn, 1);
    // ---- layer 2 ----
    gemm64<<<gemmGrid, blk, 0, stream>>>(bufB, w2, bufA, Nn, H);
    agg_csr4<<<aggGrid, blk, 0, stream>>>(bufA, offsets, deg, csrSrc, b2, bufB, Nn, 1);
    // ---- layer 3 ----
    gemm64<<<gemmGrid, blk, 0, stream>>>(bufB, w3, bufA, Nn, H);
    agg_csr4<<<aggGrid, blk, 0, stream>>>(bufA, offsets, deg, csrSrc, b3, bufB, Nn, 0);

    // ---- segmented mean pool ----
    pool_seg<<<G, blk, 0, stream>>>(bufB, gstart, gcnt, pooled);

    // ---- head ----
    head_kernel<<<divUp(G, 256), blk, 0, stream>>>(pooled, dw1, db1, dw2, db2,
                                                   dw3, db3, (float*)d_out, G);
}

// Round 4
// 343.768 us; speedup vs baseline: 2.3176x; 1.0434x over previous
//
#include <hip/hip_runtime.h>
#include <hip/hip_bf16.h>

// GCN: 3x (X@W -> bf16 support -> CSR-gather agg (fp32 accum) + bias (+relu))
//      -> segmented mean-pool -> MLP head
// CSR built on-device per launch. batch[] sorted -> pool is contiguous segments.

static inline int divUp(int a, int b) { return (a + b - 1) / b; }

__device__ __forceinline__ float bf16_to_f(unsigned short h) {
    unsigned int u = ((unsigned int)h) << 16;
    return __builtin_bit_cast(float, u);
}
__device__ __forceinline__ unsigned short f_to_bf16(float f) {
    unsigned int u = __builtin_bit_cast(unsigned int, f);
    unsigned int r = (u + 0x7FFFu + ((u >> 16) & 1u)) >> 16;  // RNE
    return (unsigned short)r;
}

// ---------------- GEMM: out_bf16[N,64] = X[N,K] @ W[K,64] ----------------
__global__ __launch_bounds__(256) void gemm64_b(const float* __restrict__ X,
                                                const float* __restrict__ W,
                                                unsigned short* __restrict__ out,
                                                int Nrows, int K) {
    __shared__ float As[32][68];
    __shared__ float Bs[128 * 64];

    const int tid = threadIdx.x;
    const int tx = tid & 15;
    const int ty = tid >> 4;
    const int m0 = blockIdx.x * 64;

    const int wElems = K * 64;
    for (int idx = tid * 4; idx < wElems; idx += 256 * 4) {
        *(float4*)(&Bs[idx]) = *(const float4*)(W + idx);
    }

    float acc[4][4];
#pragma unroll
    for (int i = 0; i < 4; ++i)
#pragma unroll
        for (int j = 0; j < 4; ++j) acc[i][j] = 0.f;

    for (int k0 = 0; k0 < K; k0 += 32) {
        __syncthreads();
        for (int f = tid; f < 512; f += 256) {
            int row = f >> 3;
            int kk = (f & 7) * 4;
            int grow = m0 + row;
            float4 a4 = make_float4(0.f, 0.f, 0.f, 0.f);
            if (grow < Nrows)
                a4 = *(const float4*)(X + (size_t)grow * K + k0 + kk);
            As[kk + 0][row] = a4.x;
            As[kk + 1][row] = a4.y;
            As[kk + 2][row] = a4.z;
            As[kk + 3][row] = a4.w;
        }
        __syncthreads();
#pragma unroll
        for (int k = 0; k < 32; ++k) {
            float4 a4 = *(const float4*)(&As[k][ty * 4]);
            float4 b4 = *(const float4*)(&Bs[(k0 + k) * 64 + tx * 4]);
            float a[4] = {a4.x, a4.y, a4.z, a4.w};
            float b[4] = {b4.x, b4.y, b4.z, b4.w};
#pragma unroll
            for (int i = 0; i < 4; ++i)
#pragma unroll
                for (int j = 0; j < 4; ++j) acc[i][j] += a[i] * b[j];
        }
    }

#pragma unroll
    for (int i = 0; i < 4; ++i) {
        int row = m0 + ty * 4 + i;
        if (row < Nrows) {
            ushort4 o;
            o.x = f_to_bf16(acc[i][0]);
            o.y = f_to_bf16(acc[i][1]);
            o.z = f_to_bf16(acc[i][2]);
            o.w = f_to_bf16(acc[i][3]);
            *(ushort4*)(out + (size_t)row * 64 + tx * 4) = o;
        }
    }
}

// ---------------- CSR build ----------------
__global__ __launch_bounds__(256) void hist4_kernel(const int* __restrict__ rows,
                                                    int* __restrict__ deg, int E) {
    int stride4 = gridDim.x * blockDim.x * 4;
    for (int i0 = (blockIdx.x * blockDim.x + threadIdx.x) * 4; i0 < E; i0 += stride4) {
        if (i0 + 3 < E) {
            int4 r = *(const int4*)(rows + i0);
            atomicAdd(&deg[r.x], 1);
            atomicAdd(&deg[r.y], 1);
            atomicAdd(&deg[r.z], 1);
            atomicAdd(&deg[r.w], 1);
        } else {
            for (int j = i0; j < E; ++j) atomicAdd(&deg[rows[j]], 1);
        }
    }
}

__global__ __launch_bounds__(256) void scanA(const int* __restrict__ deg,
                                             int* __restrict__ offsets,
                                             int* __restrict__ blockSums, int Nn) {
    __shared__ int wsum[4];
    const int tid = threadIdx.x;
    const int lane = tid & 63;
    const int wid = tid >> 6;
    const int i0 = blockIdx.x * 1024 + tid * 4;

    int v[4];
#pragma unroll
    for (int j = 0; j < 4; ++j) v[j] = (i0 + j < Nn) ? deg[i0 + j] : 0;
    int t = v[0] + v[1] + v[2] + v[3];

    int x = t;
#pragma unroll
    for (int d = 1; d < 64; d <<= 1) {
        int y = __shfl_up(x, d, 64);
        if (lane >= d) x += y;
    }
    if (lane == 63) wsum[wid] = x;
    __syncthreads();
    int waveExcl = 0;
#pragma unroll
    for (int w = 0; w < 4; ++w)
        if (w < wid) waveExcl += wsum[w];

    int e = waveExcl + (x - t);
#pragma unroll
    for (int j = 0; j < 4; ++j) {
        if (i0 + j < Nn) offsets[i0 + j] = e;
        e += v[j];
    }
    if (tid == 0) blockSums[blockIdx.x] = wsum[0] + wsum[1] + wsum[2] + wsum[3];
}

__global__ void scanB(int* __restrict__ blockSums, int* __restrict__ blockOffs, int nb) {
    if (threadIdx.x == 0 && blockIdx.x == 0) {
        int run = 0;
        for (int b = 0; b < nb; ++b) {
            blockOffs[b] = run;
            run += blockSums[b];
        }
    }
}

__global__ __launch_bounds__(256) void scanC(int* __restrict__ offsets,
                                             const int* __restrict__ blockOffs,
                                             int* __restrict__ fillPos, int Nn) {
    const int i0 = blockIdx.x * 1024 + threadIdx.x * 4;
    const int add = blockOffs[blockIdx.x];
#pragma unroll
    for (int j = 0; j < 4; ++j) {
        if (i0 + j < Nn) {
            int o = offsets[i0 + j] + add;
            offsets[i0 + j] = o;
            fillPos[i0 + j] = o;
        }
    }
}

__global__ __launch_bounds__(256) void fill4_kernel(const int* __restrict__ rows,
                                                    const int* __restrict__ cols,
                                                    int* __restrict__ fillPos,
                                                    int* __restrict__ csrSrc, int E) {
    int stride4 = gridDim.x * blockDim.x * 4;
    for (int i0 = (blockIdx.x * blockDim.x + threadIdx.x) * 4; i0 < E; i0 += stride4) {
        if (i0 + 3 < E) {
            int4 r = *(const int4*)(rows + i0);
            int4 c = *(const int4*)(cols + i0);
            int p0 = atomicAdd(&fillPos[r.x], 1);
            int p1 = atomicAdd(&fillPos[r.y], 1);
            int p2 = atomicAdd(&fillPos[r.z], 1);
            int p3 = atomicAdd(&fillPos[r.w], 1);
            csrSrc[p0] = c.x;
            csrSrc[p1] = c.y;
            csrSrc[p2] = c.z;
            csrSrc[p3] = c.w;
        } else {
            for (int j = i0; j < E; ++j) {
                int pos = atomicAdd(&fillPos[rows[j]], 1);
                csrSrc[pos] = cols[j];
            }
        }
    }
}

// scalar fallbacks (used if E % 4 != 0, keeps int4 alignment assumptions safe)
__global__ __launch_bounds__(256) void hist_kernel(const int* __restrict__ rows,
                                                   int* __restrict__ deg, int E) {
    int stride = gridDim.x * blockDim.x;
    for (int e = blockIdx.x * blockDim.x + threadIdx.x; e < E; e += stride)
        atomicAdd(&deg[rows[e]], 1);
}
__global__ __launch_bounds__(256) void fill_kernel(const int* __restrict__ rows,
                                                   const int* __restrict__ cols,
                                                   int* __restrict__ fillPos,
                                                   int* __restrict__ csrSrc, int E) {
    int stride = gridDim.x * blockDim.x;
    for (int e = blockIdx.x * blockDim.x + threadIdx.x; e < E; e += stride) {
        int pos = atomicAdd(&fillPos[rows[e]], 1);
        csrSrc[pos] = cols[e];
    }
}

// ---------------- CSR aggregation (bf16 support -> fp32 out) ----------------
// One wave per node; 4 subgroups of 16 lanes; lane covers 4 columns (8B bf16 load).
__global__ __launch_bounds__(256) void agg_csr_b(const unsigned short* __restrict__ support,
                                                 const int* __restrict__ offsets,
                                                 const int* __restrict__ deg,
                                                 const int* __restrict__ csrSrc,
                                                 const float* __restrict__ bias,
                                                 float* __restrict__ out,
                                                 int Nn, int doRelu) {
    const int lane = threadIdx.x & 63;
    const int node = blockIdx.x * 4 + (threadIdx.x >> 6);
    if (node >= Nn) return;
    const int off = offsets[node];
    const int d = deg[node];
    const int sub = lane >> 4;
    const int sl = lane & 15;

    float4 acc = make_float4(0.f, 0.f, 0.f, 0.f);
    for (int i = sub; i < d; i += 4) {
        int s = csrSrc[off + i];
        ushort4 v = *(const ushort4*)(support + (size_t)s * 64 + sl * 4);
        acc.x += bf16_to_f(v.x);
        acc.y += bf16_to_f(v.y);
        acc.z += bf16_to_f(v.z);
        acc.w += bf16_to_f(v.w);
    }
    acc.x += __shfl_xor(acc.x, 16); acc.y += __shfl_xor(acc.y, 16);
    acc.z += __shfl_xor(acc.z, 16); acc.w += __shfl_xor(acc.w, 16);
    acc.x += __shfl_xor(acc.x, 32); acc.y += __shfl_xor(acc.y, 32);
    acc.z += __shfl_xor(acc.z, 32); acc.w += __shfl_xor(acc.w, 32);

    if (sub == 0) {
        float4 b4 = *(const float4*)(bias + sl * 4);
        float4 o;
        o.x = acc.x + b4.x; o.y = acc.y + b4.y;
        o.z = acc.z + b4.z; o.w = acc.w + b4.w;
        if (doRelu) {
            o.x = fmaxf(o.x, 0.f); o.y = fmaxf(o.y, 0.f);
            o.z = fmaxf(o.z, 0.f); o.w = fmaxf(o.w, 0.f);
        }
        *(float4*)(out + (size_t)node * 64 + sl * 4) = o;
    }
}

// ---------------- graph bounds via binary search on sorted batch ----------------
__global__ __launch_bounds__(256) void graph_bounds(const int* __restrict__ batch,
                                                    int Nn, int* __restrict__ gstart,
                                                    int* __restrict__ gcnt, int G) {
    int g = blockIdx.x * blockDim.x + threadIdx.x;
    if (g >= G) return;
    int lo = 0, hi = Nn;
    while (lo < hi) { int mid = (lo + hi) >> 1; if (batch[mid] < g) lo = mid + 1; else hi = mid; }
    int s = lo;
    hi = Nn;
    while (lo < hi) { int mid = (lo + hi) >> 1; if (batch[mid] < g + 1) lo = mid + 1; else hi = mid; }
    gstart[g] = s;
    gcnt[g] = lo - s;
}

// ---------------- segmented mean pool: one block per graph ----------------
__global__ __launch_bounds__(256) void pool_seg(const float* __restrict__ x,
                                                const int* __restrict__ gstart,
                                                const int* __restrict__ gcnt,
                                                float* __restrict__ pooled) {
    __shared__ float red[4][64];
    const int g = blockIdx.x;
    const int lane = threadIdx.x & 63;
    const int wid = threadIdx.x >> 6;
    const int s = gstart[g];
    const int c = gcnt[g];

    float acc = 0.f;
    for (int i = s + wid; i < s + c; i += 4)
        acc += x[(size_t)i * 64 + lane];
    red[wid][lane] = acc;
    __syncthreads();
    if (wid == 0) {
        float v = red[0][lane] + red[1][lane] + red[2][lane] + red[3][lane];
        pooled[(size_t)g * 64 + lane] = v / fmaxf((float)c, 1.f);
    }
}

// ---------------- MLP head ----------------
__global__ __launch_bounds__(256) void head_kernel(const float* __restrict__ pooled,
                                                   const float* __restrict__ dw1,
                                                   const float* __restrict__ db1,
                                                   const float* __restrict__ dw2,
                                                   const float* __restrict__ db2,
                                                   const float* __restrict__ dw3,
                                                   const float* __restrict__ db3,
                                                   float* __restrict__ out, int G) {
    int g = blockIdx.x * blockDim.x + threadIdx.x;
    if (g >= G) return;

    float m[64];
#pragma unroll
    for (int k = 0; k < 64; ++k) m[k] = pooled[(size_t)g * 64 + k];

    float h1[16];
#pragma unroll
    for (int j = 0; j < 16; ++j) h1[j] = db1[j];
    for (int k = 0; k < 64; ++k) {
        float mv = m[k];
#pragma unroll
        for (int j = 0; j < 16; ++j) h1[j] += mv * dw1[k * 16 + j];
    }
#pragma unroll
    for (int j = 0; j < 16; ++j) h1[j] = fmaxf(h1[j], 0.f);

    float h2[8];
#pragma unroll
    for (int j = 0; j < 8; ++j) h2[j] = db2[j];
#pragma unroll
    for (int k = 0; k < 16; ++k) {
        float hv = h1[k];
#pragma unroll
        for (int j = 0; j < 8; ++j) h2[j] += hv * dw2[k * 8 + j];
    }
#pragma unroll
    for (int j = 0; j < 8; ++j) h2[j] = fmaxf(h2[j], 0.f);

    float z = db3[0];
#pragma unroll
    for (int k = 0; k < 8; ++k) z += h2[k] * dw3[k];
    out[g] = 1.0f / (1.0f + expf(-z));
}

extern "C" void kernel_launch(void* const* d_in, const int* in_sizes, int n_in,
                              void* d_out, int out_size, void* d_ws, size_t ws_size,
                              hipStream_t stream) {
    const float* feat = (const float*)d_in[0];
    const int* eidx   = (const int*)d_in[1];
    const int* batch  = (const int*)d_in[2];
    const float* w1 = (const float*)d_in[3];
    const float* b1 = (const float*)d_in[4];
    const float* w2 = (const float*)d_in[5];
    const float* b2 = (const float*)d_in[6];
    const float* w3 = (const float*)d_in[7];
    const float* b3 = (const float*)d_in[8];
    const float* dw1 = (const float*)d_in[9];
    const float* db1 = (const float*)d_in[10];
    const float* dw2 = (const float*)d_in[11];
    const float* db2 = (const float*)d_in[12];
    const float* dw3 = (const float*)d_in[13];
    const float* db3 = (const float*)d_in[14];

    const int H = in_sizes[4];              // 64
    const int F = in_sizes[3] / H;          // 128
    const int Nn = in_sizes[0] / F;         // 100000
    const int E = in_sizes[1] / 2;          // 800000
    const int G = out_size;                 // 512

    const int* rows = eidx;
    const int* cols = eidx + E;

    // workspace layout
    unsigned short* supp = (unsigned short*)d_ws;       // bf16 support [N,64]
    float* bufB = (float*)(supp + (size_t)Nn * H);      // fp32 x [N,64]
    float* pooled = bufB + (size_t)Nn * H;              // [G,64]
    int* deg = (int*)(pooled + (size_t)G * H);
    int* offsets = deg + Nn;
    int* fillPos = offsets + Nn;
    int* csrSrc = fillPos + Nn;
    int* blockSums = csrSrc + E;
    int* blockOffs = blockSums + 256;
    int* gstart = blockOffs + 256;
    int* gcnt = gstart + G;

    dim3 blk(256);
    const int gemmGrid = divUp(Nn, 64);
    const int aggGrid = divUp(Nn, 4);
    const int nb = divUp(Nn, 1024);
    const bool vec4 = (E % 4) == 0;

    // ---- CSR build + graph bounds ----
    hipMemsetAsync(deg, 0, (size_t)Nn * sizeof(int), stream);
    if (vec4)
        hist4_kernel<<<1024, blk, 0, stream>>>(rows, deg, E);
    else
        hist_kernel<<<2048, blk, 0, stream>>>(rows, deg, E);
    scanA<<<nb, blk, 0, stream>>>(deg, offsets, blockSums, Nn);
    scanB<<<1, 64, 0, stream>>>(blockSums, blockOffs, nb);
    scanC<<<nb, blk, 0, stream>>>(offsets, blockOffs, fillPos, Nn);
    if (vec4)
        fill4_kernel<<<1024, blk, 0, stream>>>(rows, cols, fillPos, csrSrc, E);
    else
        fill_kernel<<<2048, blk, 0, stream>>>(rows, cols, fillPos, csrSrc, E);
    graph_bounds<<<divUp(G, 256), blk, 0, stream>>>(batch, Nn, gstart, gcnt, G);

    // ---- layer 1 ----
    gemm64_b<<<gemmGrid, blk, 0, stream>>>(feat, w1, supp, Nn, F);
    agg_csr_b<<<aggGrid, blk, 0, stream>>>(supp, offsets, deg, csrSrc, b1, bufB, Nn, 1);
    // ---- layer 2 ----
    gemm64_b<<<gemmGrid, blk, 0, stream>>>(bufB, w2, supp, Nn, H);
    agg_csr_b<<<aggGrid, blk, 0, stream>>>(supp, offsets, deg, csrSrc, b2, bufB, Nn, 1);
    // ---- layer 3 ----
    gemm64_b<<<gemmGrid, blk, 0, stream>>>(bufB, w3, supp, Nn, H);
    agg_csr_b<<<aggGrid, blk, 0, stream>>>(supp, offsets, deg, csrSrc, b3, bufB, Nn, 0);

    // ---- segmented mean pool ----
    pool_seg<<<G, blk, 0, stream>>>(bufB, gstart, gcnt, pooled);

    // ---- head ----
    head_kernel<<<divUp(G, 256), blk, 0, stream>>>(pooled, dw1, db1, dw2, db2,
                                                   dw3, db3, (float*)d_out, G);
}

// Round 5
// 335.009 us; speedup vs baseline: 2.3782x; 1.0261x over previous
//
#include <hip/hip_runtime.h>
#include <hip/hip_bf16.h>

// GCN: 3x (X@W -> bf16 support -> CSR-gather agg (fp32 accum) -> bf16 x)
//      -> segmented mean-pool -> MLP head
// CSR built per launch with XCD-partitioned scatter (blockIdx&7 == XCD heuristic;
// wrong mapping costs speed only). batch[] sorted -> pool is contiguous segments.

static inline int divUp(int a, int b) { return (a + b - 1) / b; }

#define NXCD 8

__device__ __forceinline__ float bf16_to_f(unsigned short h) {
    unsigned int u = ((unsigned int)h) << 16;
    return __builtin_bit_cast(float, u);
}
__device__ __forceinline__ unsigned short f_to_bf16(float f) {
    unsigned int u = __builtin_bit_cast(unsigned int, f);
    unsigned int r = (u + 0x7FFFu + ((u >> 16) & 1u)) >> 16;  // RNE
    return (unsigned short)r;
}

// ---------------- GEMM (A fp32): out_bf16[N,64] = X[N,K] @ W[K,64] ----------------
__global__ __launch_bounds__(256) void gemm64_f(const float* __restrict__ X,
                                                const float* __restrict__ W,
                                                unsigned short* __restrict__ out,
                                                int Nrows, int K) {
    __shared__ float As[32][68];
    __shared__ float Bs[128 * 64];

    const int tid = threadIdx.x;
    const int tx = tid & 15;
    const int ty = tid >> 4;
    const int m0 = blockIdx.x * 64;

    const int wElems = K * 64;
    for (int idx = tid * 4; idx < wElems; idx += 256 * 4)
        *(float4*)(&Bs[idx]) = *(const float4*)(W + idx);

    float acc[4][4];
#pragma unroll
    for (int i = 0; i < 4; ++i)
#pragma unroll
        for (int j = 0; j < 4; ++j) acc[i][j] = 0.f;

    for (int k0 = 0; k0 < K; k0 += 32) {
        __syncthreads();
        for (int f = tid; f < 512; f += 256) {
            int row = f >> 3;
            int kk = (f & 7) * 4;
            int grow = m0 + row;
            float4 a4 = make_float4(0.f, 0.f, 0.f, 0.f);
            if (grow < Nrows)
                a4 = *(const float4*)(X + (size_t)grow * K + k0 + kk);
            As[kk + 0][row] = a4.x;
            As[kk + 1][row] = a4.y;
            As[kk + 2][row] = a4.z;
            As[kk + 3][row] = a4.w;
        }
        __syncthreads();
#pragma unroll
        for (int k = 0; k < 32; ++k) {
            float4 a4 = *(const float4*)(&As[k][ty * 4]);
            float4 b4 = *(const float4*)(&Bs[(k0 + k) * 64 + tx * 4]);
            float a[4] = {a4.x, a4.y, a4.z, a4.w};
            float b[4] = {b4.x, b4.y, b4.z, b4.w};
#pragma unroll
            for (int i = 0; i < 4; ++i)
#pragma unroll
                for (int j = 0; j < 4; ++j) acc[i][j] += a[i] * b[j];
        }
    }

#pragma unroll
    for (int i = 0; i < 4; ++i) {
        int row = m0 + ty * 4 + i;
        if (row < Nrows) {
            ushort4 o;
            o.x = f_to_bf16(acc[i][0]);
            o.y = f_to_bf16(acc[i][1]);
            o.z = f_to_bf16(acc[i][2]);
            o.w = f_to_bf16(acc[i][3]);
            *(ushort4*)(out + (size_t)row * 64 + tx * 4) = o;
        }
    }
}

// ---------------- GEMM (A bf16): out_bf16[N,64] = X[N,64] @ W[64,64] ----------------
__global__ __launch_bounds__(256) void gemm64_h(const unsigned short* __restrict__ X,
                                                const float* __restrict__ W,
                                                unsigned short* __restrict__ out,
                                                int Nrows, int K) {
    __shared__ float As[32][68];
    __shared__ float Bs[128 * 64];

    const int tid = threadIdx.x;
    const int tx = tid & 15;
    const int ty = tid >> 4;
    const int m0 = blockIdx.x * 64;

    const int wElems = K * 64;
    for (int idx = tid * 4; idx < wElems; idx += 256 * 4)
        *(float4*)(&Bs[idx]) = *(const float4*)(W + idx);

    float acc[4][4];
#pragma unroll
    for (int i = 0; i < 4; ++i)
#pragma unroll
        for (int j = 0; j < 4; ++j) acc[i][j] = 0.f;

    for (int k0 = 0; k0 < K; k0 += 32) {
        __syncthreads();
        for (int f = tid; f < 512; f += 256) {
            int row = f >> 3;
            int kk = (f & 7) * 4;
            int grow = m0 + row;
            float a0 = 0.f, a1 = 0.f, a2 = 0.f, a3 = 0.f;
            if (grow < Nrows) {
                ushort4 u = *(const ushort4*)(X + (size_t)grow * K + k0 + kk);
                a0 = bf16_to_f(u.x); a1 = bf16_to_f(u.y);
                a2 = bf16_to_f(u.z); a3 = bf16_to_f(u.w);
            }
            As[kk + 0][row] = a0;
            As[kk + 1][row] = a1;
            As[kk + 2][row] = a2;
            As[kk + 3][row] = a3;
        }
        __syncthreads();
#pragma unroll
        for (int k = 0; k < 32; ++k) {
            float4 a4 = *(const float4*)(&As[k][ty * 4]);
            float4 b4 = *(const float4*)(&Bs[(k0 + k) * 64 + tx * 4]);
            float a[4] = {a4.x, a4.y, a4.z, a4.w};
            float b[4] = {b4.x, b4.y, b4.z, b4.w};
#pragma unroll
            for (int i = 0; i < 4; ++i)
#pragma unroll
                for (int j = 0; j < 4; ++j) acc[i][j] += a[i] * b[j];
        }
    }

#pragma unroll
    for (int i = 0; i < 4; ++i) {
        int row = m0 + ty * 4 + i;
        if (row < Nrows) {
            ushort4 o;
            o.x = f_to_bf16(acc[i][0]);
            o.y = f_to_bf16(acc[i][1]);
            o.z = f_to_bf16(acc[i][2]);
            o.w = f_to_bf16(acc[i][3]);
            *(ushort4*)(out + (size_t)row * 64 + tx * 4) = o;
        }
    }
}

// ---------------- CSR build (XCD-partitioned scatters) ----------------
// Node range p = [p*Nn/8, (p+1)*Nn/8); block's partition = blockIdx & 7 so all
// blocks on one XCD write one contiguous slice -> L2-local, no cross-XCD line
// ping-pong. Each partition group grid-strides the full edge list.
__global__ __launch_bounds__(256) void hist_part(const int* __restrict__ rows,
                                                 int* __restrict__ deg, int E, int Nn) {
    const int p = blockIdx.x & (NXCD - 1);
    const int lo = (int)((long)p * Nn / NXCD);
    const int hi = (int)((long)(p + 1) * Nn / NXCD);
    const int nb = gridDim.x >> 3;
    const int cb = blockIdx.x >> 3;
    const int stride4 = nb * blockDim.x * 4;
    for (int i0 = (cb * blockDim.x + threadIdx.x) * 4; i0 < E; i0 += stride4) {
        if (i0 + 3 < E) {
            int4 r = *(const int4*)(rows + i0);
            if (r.x >= lo && r.x < hi) atomicAdd(&deg[r.x], 1);
            if (r.y >= lo && r.y < hi) atomicAdd(&deg[r.y], 1);
            if (r.z >= lo && r.z < hi) atomicAdd(&deg[r.z], 1);
            if (r.w >= lo && r.w < hi) atomicAdd(&deg[r.w], 1);
        } else {
            for (int j = i0; j < E; ++j) {
                int r = rows[j];
                if (r >= lo && r < hi) atomicAdd(&deg[r], 1);
            }
        }
    }
}

__global__ __launch_bounds__(256) void fill_part(const int* __restrict__ rows,
                                                 const int* __restrict__ cols,
                                                 int* __restrict__ fillPos,
                                                 int* __restrict__ csrSrc, int E, int Nn) {
    const int p = blockIdx.x & (NXCD - 1);
    const int lo = (int)((long)p * Nn / NXCD);
    const int hi = (int)((long)(p + 1) * Nn / NXCD);
    const int nb = gridDim.x >> 3;
    const int cb = blockIdx.x >> 3;
    const int stride4 = nb * blockDim.x * 4;
    for (int i0 = (cb * blockDim.x + threadIdx.x) * 4; i0 < E; i0 += stride4) {
        if (i0 + 3 < E) {
            int4 r = *(const int4*)(rows + i0);
            int4 c = *(const int4*)(cols + i0);
            if (r.x >= lo && r.x < hi) { int q = atomicAdd(&fillPos[r.x], 1); csrSrc[q] = c.x; }
            if (r.y >= lo && r.y < hi) { int q = atomicAdd(&fillPos[r.y], 1); csrSrc[q] = c.y; }
            if (r.z >= lo && r.z < hi) { int q = atomicAdd(&fillPos[r.z], 1); csrSrc[q] = c.z; }
            if (r.w >= lo && r.w < hi) { int q = atomicAdd(&fillPos[r.w], 1); csrSrc[q] = c.w; }
        } else {
            for (int j = i0; j < E; ++j) {
                int r = rows[j];
                if (r >= lo && r < hi) { int q = atomicAdd(&fillPos[r], 1); csrSrc[q] = cols[j]; }
            }
        }
    }
}

__global__ __launch_bounds__(256) void scanA(const int* __restrict__ deg,
                                             int* __restrict__ offsets,
                                             int* __restrict__ blockSums, int Nn) {
    __shared__ int wsum[4];
    const int tid = threadIdx.x;
    const int lane = tid & 63;
    const int wid = tid >> 6;
    const int i0 = blockIdx.x * 1024 + tid * 4;

    int v[4];
#pragma unroll
    for (int j = 0; j < 4; ++j) v[j] = (i0 + j < Nn) ? deg[i0 + j] : 0;
    int t = v[0] + v[1] + v[2] + v[3];

    int x = t;
#pragma unroll
    for (int d = 1; d < 64; d <<= 1) {
        int y = __shfl_up(x, d, 64);
        if (lane >= d) x += y;
    }
    if (lane == 63) wsum[wid] = x;
    __syncthreads();
    int waveExcl = 0;
#pragma unroll
    for (int w = 0; w < 4; ++w)
        if (w < wid) waveExcl += wsum[w];

    int e = waveExcl + (x - t);
#pragma unroll
    for (int j = 0; j < 4; ++j) {
        if (i0 + j < Nn) offsets[i0 + j] = e;
        e += v[j];
    }
    if (tid == 0) blockSums[blockIdx.x] = wsum[0] + wsum[1] + wsum[2] + wsum[3];
}

__global__ void scanB(int* __restrict__ blockSums, int* __restrict__ blockOffs, int nb) {
    if (threadIdx.x == 0 && blockIdx.x == 0) {
        int run = 0;
        for (int b = 0; b < nb; ++b) {
            blockOffs[b] = run;
            run += blockSums[b];
        }
    }
}

__global__ __launch_bounds__(256) void scanC(int* __restrict__ offsets,
                                             const int* __restrict__ blockOffs,
                                             int* __restrict__ fillPos, int Nn) {
    const int i0 = blockIdx.x * 1024 + threadIdx.x * 4;
    const int add = blockOffs[blockIdx.x];
#pragma unroll
    for (int j = 0; j < 4; ++j) {
        if (i0 + j < Nn) {
            int o = offsets[i0 + j] + add;
            offsets[i0 + j] = o;
            fillPos[i0 + j] = o;
        }
    }
}

// ---------------- CSR aggregation (bf16 support -> fp32 accum -> bf16 out) ----------------
__global__ __launch_bounds__(256) void agg_csr_b(const unsigned short* __restrict__ support,
                                                 const int* __restrict__ offsets,
                                                 const int* __restrict__ deg,
                                                 const int* __restrict__ csrSrc,
                                                 const float* __restrict__ bias,
                                                 unsigned short* __restrict__ out,
                                                 int Nn, int doRelu) {
    const int lane = threadIdx.x & 63;
    const int node = blockIdx.x * 4 + (threadIdx.x >> 6);
    if (node >= Nn) return;
    const int off = offsets[node];
    const int d = deg[node];
    const int sub = lane >> 4;
    const int sl = lane & 15;

    float4 acc = make_float4(0.f, 0.f, 0.f, 0.f);
    for (int i = sub; i < d; i += 4) {
        int s = csrSrc[off + i];
        ushort4 v = *(const ushort4*)(support + (size_t)s * 64 + sl * 4);
        acc.x += bf16_to_f(v.x);
        acc.y += bf16_to_f(v.y);
        acc.z += bf16_to_f(v.z);
        acc.w += bf16_to_f(v.w);
    }
    acc.x += __shfl_xor(acc.x, 16); acc.y += __shfl_xor(acc.y, 16);
    acc.z += __shfl_xor(acc.z, 16); acc.w += __shfl_xor(acc.w, 16);
    acc.x += __shfl_xor(acc.x, 32); acc.y += __shfl_xor(acc.y, 32);
    acc.z += __shfl_xor(acc.z, 32); acc.w += __shfl_xor(acc.w, 32);

    if (sub == 0) {
        float4 b4 = *(const float4*)(bias + sl * 4);
        float ox = acc.x + b4.x, oy = acc.y + b4.y;
        float oz = acc.z + b4.z, ow = acc.w + b4.w;
        if (doRelu) {
            ox = fmaxf(ox, 0.f); oy = fmaxf(oy, 0.f);
            oz = fmaxf(oz, 0.f); ow = fmaxf(ow, 0.f);
        }
        ushort4 o;
        o.x = f_to_bf16(ox); o.y = f_to_bf16(oy);
        o.z = f_to_bf16(oz); o.w = f_to_bf16(ow);
        *(ushort4*)(out + (size_t)node * 64 + sl * 4) = o;
    }
}

// ---------------- graph bounds via binary search on sorted batch ----------------
__global__ __launch_bounds__(256) void graph_bounds(const int* __restrict__ batch,
                                                    int Nn, int* __restrict__ gstart,
                                                    int* __restrict__ gcnt, int G) {
    int g = blockIdx.x * blockDim.x + threadIdx.x;
    if (g >= G) return;
    int lo = 0, hi = Nn;
    while (lo < hi) { int mid = (lo + hi) >> 1; if (batch[mid] < g) lo = mid + 1; else hi = mid; }
    int s = lo;
    hi = Nn;
    while (lo < hi) { int mid = (lo + hi) >> 1; if (batch[mid] < g + 1) lo = mid + 1; else hi = mid; }
    gstart[g] = s;
    gcnt[g] = lo - s;
}

// ---------------- segmented mean pool (bf16 x): one block per graph ----------------
__global__ __launch_bounds__(256) void pool_seg_b(const unsigned short* __restrict__ x,
                                                  const int* __restrict__ gstart,
                                                  const int* __restrict__ gcnt,
                                                  float* __restrict__ pooled) {
    __shared__ float red[4][64];
    const int g = blockIdx.x;
    const int lane = threadIdx.x & 63;
    const int wid = threadIdx.x >> 6;
    const int s = gstart[g];
    const int c = gcnt[g];

    float acc = 0.f;
    for (int i = s + wid; i < s + c; i += 4)
        acc += bf16_to_f(x[(size_t)i * 64 + lane]);
    red[wid][lane] = acc;
    __syncthreads();
    if (wid == 0) {
        float v = red[0][lane] + red[1][lane] + red[2][lane] + red[3][lane];
        pooled[(size_t)g * 64 + lane] = v / fmaxf((float)c, 1.f);
    }
}

// ---------------- MLP head ----------------
__global__ __launch_bounds__(256) void head_kernel(const float* __restrict__ pooled,
                                                   const float* __restrict__ dw1,
                                                   const float* __restrict__ db1,
                                                   const float* __restrict__ dw2,
                                                   const float* __restrict__ db2,
                                                   const float* __restrict__ dw3,
                                                   const float* __restrict__ db3,
                                                   float* __restrict__ out, int G) {
    int g = blockIdx.x * blockDim.x + threadIdx.x;
    if (g >= G) return;

    float m[64];
#pragma unroll
    for (int k = 0; k < 64; ++k) m[k] = pooled[(size_t)g * 64 + k];

    float h1[16];
#pragma unroll
    for (int j = 0; j < 16; ++j) h1[j] = db1[j];
    for (int k = 0; k < 64; ++k) {
        float mv = m[k];
#pragma unroll
        for (int j = 0; j < 16; ++j) h1[j] += mv * dw1[k * 16 + j];
    }
#pragma unroll
    for (int j = 0; j < 16; ++j) h1[j] = fmaxf(h1[j], 0.f);

    float h2[8];
#pragma unroll
    for (int j = 0; j < 8; ++j) h2[j] = db2[j];
#pragma unroll
    for (int k = 0; k < 16; ++k) {
        float hv = h1[k];
#pragma unroll
        for (int j = 0; j < 8; ++j) h2[j] += hv * dw2[k * 8 + j];
    }
#pragma unroll
    for (int j = 0; j < 8; ++j) h2[j] = fmaxf(h2[j], 0.f);

    float z = db3[0];
#pragma unroll
    for (int k = 0; k < 8; ++k) z += h2[k] * dw3[k];
    out[g] = 1.0f / (1.0f + expf(-z));
}

extern "C" void kernel_launch(void* const* d_in, const int* in_sizes, int n_in,
                              void* d_out, int out_size, void* d_ws, size_t ws_size,
                              hipStream_t stream) {
    const float* feat = (const float*)d_in[0];
    const int* eidx   = (const int*)d_in[1];
    const int* batch  = (const int*)d_in[2];
    const float* w1 = (const float*)d_in[3];
    const float* b1 = (const float*)d_in[4];
    const float* w2 = (const float*)d_in[5];
    const float* b2 = (const float*)d_in[6];
    const float* w3 = (const float*)d_in[7];
    const float* b3 = (const float*)d_in[8];
    const float* dw1 = (const float*)d_in[9];
    const float* db1 = (const float*)d_in[10];
    const float* dw2 = (const float*)d_in[11];
    const float* db2 = (const float*)d_in[12];
    const float* dw3 = (const float*)d_in[13];
    const float* db3 = (const float*)d_in[14];

    const int H = in_sizes[4];              // 64
    const int F = in_sizes[3] / H;          // 128
    const int Nn = in_sizes[0] / F;         // 100000
    const int E = in_sizes[1] / 2;          // 800000
    const int G = out_size;                 // 512

    const int* rows = eidx;
    const int* cols = eidx + E;

    // workspace layout (all bf16 node tensors)
    unsigned short* supp = (unsigned short*)d_ws;        // bf16 support [N,64]
    unsigned short* xb = supp + (size_t)Nn * H;          // bf16 x [N,64]
    float* pooled = (float*)(xb + (size_t)Nn * H);       // [G,64]
    int* deg = (int*)(pooled + (size_t)G * H);
    int* offsets = deg + Nn;
    int* fillPos = offsets + Nn;
    int* csrSrc = fillPos + Nn;
    int* blockSums = csrSrc + E;
    int* blockOffs = blockSums + 256;
    int* gstart = blockOffs + 256;
    int* gcnt = gstart + G;

    dim3 blk(256);
    const int gemmGrid = divUp(Nn, 64);
    const int aggGrid = divUp(Nn, 4);
    const int nb = divUp(Nn, 1024);

    // ---- CSR build (XCD-partitioned) + graph bounds ----
    hipMemsetAsync(deg, 0, (size_t)Nn * sizeof(int), stream);
    hist_part<<<2048, blk, 0, stream>>>(rows, deg, E, Nn);
    scanA<<<nb, blk, 0, stream>>>(deg, offsets, blockSums, Nn);
    scanB<<<1, 64, 0, stream>>>(blockSums, blockOffs, nb);
    scanC<<<nb, blk, 0, stream>>>(offsets, blockOffs, fillPos, Nn);
    fill_part<<<2048, blk, 0, stream>>>(rows, cols, fillPos, csrSrc, E, Nn);
    graph_bounds<<<divUp(G, 256), blk, 0, stream>>>(batch, Nn, gstart, gcnt, G);

    // ---- layer 1 ----
    gemm64_f<<<gemmGrid, blk, 0, stream>>>(feat, w1, supp, Nn, F);
    agg_csr_b<<<aggGrid, blk, 0, stream>>>(supp, offsets, deg, csrSrc, b1, xb, Nn, 1);
    // ---- layer 2 ----
    gemm64_h<<<gemmGrid, blk, 0, stream>>>(xb, w2, supp, Nn, H);
    agg_csr_b<<<aggGrid, blk, 0, stream>>>(supp, offsets, deg, csrSrc, b2, xb, Nn, 1);
    // ---- layer 3 ----
    gemm64_h<<<gemmGrid, blk, 0, stream>>>(xb, w3, supp, Nn, H);
    agg_csr_b<<<aggGrid, blk, 0, stream>>>(supp, offsets, deg, csrSrc, b3, xb, Nn, 0);

    // ---- segmented mean pool ----
    pool_seg_b<<<G, blk, 0, stream>>>(xb, gstart, gcnt, pooled);

    // ---- head ----
    head_kernel<<<divUp(G, 256), blk, 0, stream>>>(pooled, dw1, db1, dw2, db2,
                                                   dw3, db3, (float*)d_out, G);
}

// Round 6
// 296.060 us; speedup vs baseline: 2.6911x; 1.1316x over previous
//
#include <hip/hip_runtime.h>
#include <hip/hip_bf16.h>

// GCN: 3x (MFMA bf16 GEMM -> CSR-gather agg (fp32 accum) -> bf16 x)
//      -> segmented mean-pool -> MLP head
// CSR built per launch with XCD-partitioned scatter. batch[] sorted.

static inline int divUp(int a, int b) { return (a + b - 1) / b; }

#define NXCD 8

using short8 = __attribute__((ext_vector_type(8))) short;
using f32x4 = __attribute__((ext_vector_type(4))) float;

__device__ __forceinline__ float bf16_to_f(unsigned short h) {
    unsigned int u = ((unsigned int)h) << 16;
    return __builtin_bit_cast(float, u);
}
__device__ __forceinline__ unsigned short f_to_bf16(float f) {
    unsigned int u = __builtin_bit_cast(unsigned int, f);
    unsigned int r = (u + 0x7FFFu + ((u >> 16) & 1u)) >> 16;  // RNE
    return (unsigned short)r;
}

// ---------------- MFMA GEMM: out_bf16[N,64] = X[N,K] @ W[K,64] ----------------
// 64x64 block tile, 4 waves (each: 16 rows x 64 cols), K in {64,128}.
// A and W^T staged in LDS as bf16, 16B-chunk XOR swizzle (chunk ^ (row & (CPR-1))).
template <int K, bool AFP32>
__global__ __launch_bounds__(256) void mfma_gemm(const void* __restrict__ Xv,
                                                 const float* __restrict__ W,
                                                 unsigned short* __restrict__ out,
                                                 int Nrows) {
    constexpr int CPR = K / 8;   // 16B chunks per row
    constexpr int MSK = CPR - 1;
    __shared__ unsigned char smem[256 * K];  // A(128K/2)=64*K*2 B + B same
    unsigned short* Al = (unsigned short*)smem;              // [64][K] swizzled
    unsigned short* Bl = (unsigned short*)(smem + 128 * K);  // [64 cols][K] swizzled

    const int tid = threadIdx.x;
    const int m0 = blockIdx.x * 64;

    // ---- stage A (64 rows x K, bf16, swizzled chunks) ----
    if (AFP32) {
        const float* X = (const float*)Xv;
        for (int f = tid; f < 64 * CPR; f += 256) {
            int r = f / CPR, ck = f % CPR;
            int grow = m0 + r;
            float4 x0 = make_float4(0.f, 0.f, 0.f, 0.f);
            float4 x1 = make_float4(0.f, 0.f, 0.f, 0.f);
            if (grow < Nrows) {
                const float* p = X + (size_t)grow * K + ck * 8;
                x0 = *(const float4*)p;
                x1 = *(const float4*)(p + 4);
            }
            ushort4 h0, h1;
            h0.x = f_to_bf16(x0.x); h0.y = f_to_bf16(x0.y);
            h0.z = f_to_bf16(x0.z); h0.w = f_to_bf16(x0.w);
            h1.x = f_to_bf16(x1.x); h1.y = f_to_bf16(x1.y);
            h1.z = f_to_bf16(x1.z); h1.w = f_to_bf16(x1.w);
            unsigned short* dst = Al + r * K + ((ck ^ (r & MSK)) * 8);
            *(ushort4*)dst = h0;
            *(ushort4*)(dst + 4) = h1;
        }
    } else {
        const unsigned short* X = (const unsigned short*)Xv;
        for (int f = tid; f < 64 * CPR; f += 256) {
            int r = f / CPR, ck = f % CPR;
            int grow = m0 + r;
            uint4 v = make_uint4(0u, 0u, 0u, 0u);
            if (grow < Nrows) v = *(const uint4*)(X + (size_t)grow * K + ck * 8);
            *(uint4*)(Al + r * K + ((ck ^ (r & MSK)) * 8)) = v;
        }
    }

    // ---- stage W transposed: Bl[col][k] (bf16, swizzled) ----
    for (int q = tid; q < 64 * CPR; q += 256) {
        int c = q / CPR, ck = q % CPR;
        const float* p = W + (size_t)ck * 8 * 64 + c;  // W[k][c], k=ck*8..+7
        ushort4 h0, h1;
        h0.x = f_to_bf16(p[0]);   h0.y = f_to_bf16(p[64]);
        h0.z = f_to_bf16(p[128]); h0.w = f_to_bf16(p[192]);
        h1.x = f_to_bf16(p[256]); h1.y = f_to_bf16(p[320]);
        h1.z = f_to_bf16(p[384]); h1.w = f_to_bf16(p[448]);
        unsigned short* dst = Bl + c * K + ((ck ^ (c & MSK)) * 8);
        *(ushort4*)dst = h0;
        *(ushort4*)(dst + 4) = h1;
    }
    __syncthreads();

    const int lane = tid & 63;
    const int w = tid >> 6;
    const int g = lane >> 4;
    const int sl = lane & 15;
    const int r0 = w * 16;

    f32x4 acc[4];
#pragma unroll
    for (int cf = 0; cf < 4; ++cf) acc[cf] = (f32x4){0.f, 0.f, 0.f, 0.f};

#pragma unroll
    for (int ks = 0; ks < K / 32; ++ks) {
        const int ar = r0 + sl;  // A fragment: row = lane&15 (+wave base)
        short8 a = *(const short8*)(Al + ar * K + (((ks * 4 + g) ^ (ar & MSK)) * 8));
#pragma unroll
        for (int cf = 0; cf < 4; ++cf) {
            const int bc = cf * 16 + sl;  // B fragment: col = lane&15
            short8 b = *(const short8*)(Bl + bc * K + (((ks * 4 + g) ^ (bc & MSK)) * 8));
            acc[cf] = __builtin_amdgcn_mfma_f32_16x16x32_bf16(a, b, acc[cf], 0, 0, 0);
        }
    }
    __syncthreads();

    // ---- epilogue: C via padded LDS (reuse smem) for coalesced stores ----
    unsigned short* Cl = (unsigned short*)smem;  // [64][72] halfwords = 9216 B
#pragma unroll
    for (int cf = 0; cf < 4; ++cf)
#pragma unroll
        for (int rg = 0; rg < 4; ++rg) {
            int row = r0 + g * 4 + rg;  // C/D: row=(lane>>4)*4+reg, col=lane&15
            Cl[row * 72 + cf * 16 + sl] = f_to_bf16(acc[cf][rg]);
        }
    __syncthreads();
    {
        int row = tid >> 2;
        int c0 = (tid & 3) * 16;
        int grow = m0 + row;
        if (grow < Nrows) {
            uint4 a = *(const uint4*)(Cl + row * 72 + c0);
            uint4 b = *(const uint4*)(Cl + row * 72 + c0 + 8);
            *(uint4*)(out + (size_t)grow * 64 + c0) = a;
            *(uint4*)(out + (size_t)grow * 64 + c0 + 8) = b;
        }
    }
}

// ---------------- CSR build (XCD-partitioned scatters) ----------------
__global__ __launch_bounds__(256) void hist_part(const int* __restrict__ rows,
                                                 int* __restrict__ deg, int E, int Nn) {
    const int p = blockIdx.x & (NXCD - 1);
    const int lo = (int)((long)p * Nn / NXCD);
    const int hi = (int)((long)(p + 1) * Nn / NXCD);
    const int nb = gridDim.x >> 3;
    const int cb = blockIdx.x >> 3;
    const int stride4 = nb * blockDim.x * 4;
    for (int i0 = (cb * blockDim.x + threadIdx.x) * 4; i0 < E; i0 += stride4) {
        if (i0 + 3 < E) {
            int4 r = *(const int4*)(rows + i0);
            if (r.x >= lo && r.x < hi) atomicAdd(&deg[r.x], 1);
            if (r.y >= lo && r.y < hi) atomicAdd(&deg[r.y], 1);
            if (r.z >= lo && r.z < hi) atomicAdd(&deg[r.z], 1);
            if (r.w >= lo && r.w < hi) atomicAdd(&deg[r.w], 1);
        } else {
            for (int j = i0; j < E; ++j) {
                int r = rows[j];
                if (r >= lo && r < hi) atomicAdd(&deg[r], 1);
            }
        }
    }
}

__global__ __launch_bounds__(256) void fill_part(const int* __restrict__ rows,
                                                 const int* __restrict__ cols,
                                                 int* __restrict__ fillPos,
                                                 int* __restrict__ csrSrc, int E, int Nn) {
    const int p = blockIdx.x & (NXCD - 1);
    const int lo = (int)((long)p * Nn / NXCD);
    const int hi = (int)((long)(p + 1) * Nn / NXCD);
    const int nb = gridDim.x >> 3;
    const int cb = blockIdx.x >> 3;
    const int stride4 = nb * blockDim.x * 4;
    for (int i0 = (cb * blockDim.x + threadIdx.x) * 4; i0 < E; i0 += stride4) {
        if (i0 + 3 < E) {
            int4 r = *(const int4*)(rows + i0);
            int4 c = *(const int4*)(cols + i0);
            if (r.x >= lo && r.x < hi) { int q = atomicAdd(&fillPos[r.x], 1); csrSrc[q] = c.x; }
            if (r.y >= lo && r.y < hi) { int q = atomicAdd(&fillPos[r.y], 1); csrSrc[q] = c.y; }
            if (r.z >= lo && r.z < hi) { int q = atomicAdd(&fillPos[r.z], 1); csrSrc[q] = c.z; }
            if (r.w >= lo && r.w < hi) { int q = atomicAdd(&fillPos[r.w], 1); csrSrc[q] = c.w; }
        } else {
            for (int j = i0; j < E; ++j) {
                int r = rows[j];
                if (r >= lo && r < hi) { int q = atomicAdd(&fillPos[r], 1); csrSrc[q] = cols[j]; }
            }
        }
    }
}

__global__ __launch_bounds__(256) void scanA(const int* __restrict__ deg,
                                             int* __restrict__ offsets,
                                             int* __restrict__ blockSums, int Nn) {
    __shared__ int wsum[4];
    const int tid = threadIdx.x;
    const int lane = tid & 63;
    const int wid = tid >> 6;
    const int i0 = blockIdx.x * 1024 + tid * 4;

    int v[4];
#pragma unroll
    for (int j = 0; j < 4; ++j) v[j] = (i0 + j < Nn) ? deg[i0 + j] : 0;
    int t = v[0] + v[1] + v[2] + v[3];

    int x = t;
#pragma unroll
    for (int d = 1; d < 64; d <<= 1) {
        int y = __shfl_up(x, d, 64);
        if (lane >= d) x += y;
    }
    if (lane == 63) wsum[wid] = x;
    __syncthreads();
    int waveExcl = 0;
#pragma unroll
    for (int w = 0; w < 4; ++w)
        if (w < wid) waveExcl += wsum[w];

    int e = waveExcl + (x - t);
#pragma unroll
    for (int j = 0; j < 4; ++j) {
        if (i0 + j < Nn) offsets[i0 + j] = e;
        e += v[j];
    }
    if (tid == 0) blockSums[blockIdx.x] = wsum[0] + wsum[1] + wsum[2] + wsum[3];
}

__global__ void scanB(int* __restrict__ blockSums, int* __restrict__ blockOffs, int nb) {
    if (threadIdx.x == 0 && blockIdx.x == 0) {
        int run = 0;
        for (int b = 0; b < nb; ++b) {
            blockOffs[b] = run;
            run += blockSums[b];
        }
    }
}

__global__ __launch_bounds__(256) void scanC(int* __restrict__ offsets,
                                             const int* __restrict__ blockOffs,
                                             int* __restrict__ fillPos, int Nn) {
    const int i0 = blockIdx.x * 1024 + threadIdx.x * 4;
    const int add = blockOffs[blockIdx.x];
#pragma unroll
    for (int j = 0; j < 4; ++j) {
        if (i0 + j < Nn) {
            int o = offsets[i0 + j] + add;
            offsets[i0 + j] = o;
            fillPos[i0 + j] = o;
        }
    }
}

// ---------------- CSR aggregation (bf16 support -> fp32 accum -> bf16 out) ----------------
// One wave per node. Coalesced index preload (first 64 edges) + shfl broadcast;
// 4 subgroups of 16 lanes; 2-deep unrolled gather (dual accumulators).
__global__ __launch_bounds__(256) void agg_csr_b(const unsigned short* __restrict__ support,
                                                 const int* __restrict__ offsets,
                                                 const int* __restrict__ deg,
                                                 const int* __restrict__ csrSrc,
                                                 const float* __restrict__ bias,
                                                 unsigned short* __restrict__ out,
                                                 int Nn, int doRelu) {
    const int lane = threadIdx.x & 63;
    const int node = blockIdx.x * 4 + (threadIdx.x >> 6);
    if (node >= Nn) return;
    const int off = offsets[node];
    const int d = deg[node];
    const int sub = lane >> 4;
    const int sl = lane & 15;

    const int d64 = d < 64 ? d : 64;
    int idx = (lane < d64) ? csrSrc[off + lane] : 0;  // one coalesced load

    float4 acc0 = make_float4(0.f, 0.f, 0.f, 0.f);
    float4 acc1 = make_float4(0.f, 0.f, 0.f, 0.f);
    for (int i = sub; i < d64; i += 8) {
        int s0 = __shfl(idx, i);
        ushort4 v0 = *(const ushort4*)(support + (size_t)s0 * 64 + sl * 4);
        if (i + 4 < d64) {
            int s1 = __shfl(idx, i + 4);
            ushort4 v1 = *(const ushort4*)(support + (size_t)s1 * 64 + sl * 4);
            acc1.x += bf16_to_f(v1.x); acc1.y += bf16_to_f(v1.y);
            acc1.z += bf16_to_f(v1.z); acc1.w += bf16_to_f(v1.w);
        }
        acc0.x += bf16_to_f(v0.x); acc0.y += bf16_to_f(v0.y);
        acc0.z += bf16_to_f(v0.z); acc0.w += bf16_to_f(v0.w);
    }
    // rare tail: degree > 64
    for (int i = 64 + sub; i < d; i += 4) {
        int s = csrSrc[off + i];
        ushort4 v = *(const ushort4*)(support + (size_t)s * 64 + sl * 4);
        acc0.x += bf16_to_f(v.x); acc0.y += bf16_to_f(v.y);
        acc0.z += bf16_to_f(v.z); acc0.w += bf16_to_f(v.w);
    }

    float4 acc;
    acc.x = acc0.x + acc1.x; acc.y = acc0.y + acc1.y;
    acc.z = acc0.z + acc1.z; acc.w = acc0.w + acc1.w;
    acc.x += __shfl_xor(acc.x, 16); acc.y += __shfl_xor(acc.y, 16);
    acc.z += __shfl_xor(acc.z, 16); acc.w += __shfl_xor(acc.w, 16);
    acc.x += __shfl_xor(acc.x, 32); acc.y += __shfl_xor(acc.y, 32);
    acc.z += __shfl_xor(acc.z, 32); acc.w += __shfl_xor(acc.w, 32);

    if (sub == 0) {
        float4 b4 = *(const float4*)(bias + sl * 4);
        float ox = acc.x + b4.x, oy = acc.y + b4.y;
        float oz = acc.z + b4.z, ow = acc.w + b4.w;
        if (doRelu) {
            ox = fmaxf(ox, 0.f); oy = fmaxf(oy, 0.f);
            oz = fmaxf(oz, 0.f); ow = fmaxf(ow, 0.f);
        }
        ushort4 o;
        o.x = f_to_bf16(ox); o.y = f_to_bf16(oy);
        o.z = f_to_bf16(oz); o.w = f_to_bf16(ow);
        *(ushort4*)(out + (size_t)node * 64 + sl * 4) = o;
    }
}

// ---------------- graph bounds via binary search on sorted batch ----------------
__global__ __launch_bounds__(256) void graph_bounds(const int* __restrict__ batch,
                                                    int Nn, int* __restrict__ gstart,
                                                    int* __restrict__ gcnt, int G) {
    int g = blockIdx.x * blockDim.x + threadIdx.x;
    if (g >= G) return;
    int lo = 0, hi = Nn;
    while (lo < hi) { int mid = (lo + hi) >> 1; if (batch[mid] < g) lo = mid + 1; else hi = mid; }
    int s = lo;
    hi = Nn;
    while (lo < hi) { int mid = (lo + hi) >> 1; if (batch[mid] < g + 1) lo = mid + 1; else hi = mid; }
    gstart[g] = s;
    gcnt[g] = lo - s;
}

// ---------------- segmented mean pool (bf16 x): one block per graph ----------------
__global__ __launch_bounds__(256) void pool_seg_b(const unsigned short* __restrict__ x,
                                                  const int* __restrict__ gstart,
                                                  const int* __restrict__ gcnt,
                                                  float* __restrict__ pooled) {
    __shared__ float red[4][64];
    const int g = blockIdx.x;
    const int lane = threadIdx.x & 63;
    const int wid = threadIdx.x >> 6;
    const int s = gstart[g];
    const int c = gcnt[g];

    float acc = 0.f;
    for (int i = s + wid; i < s + c; i += 4)
        acc += bf16_to_f(x[(size_t)i * 64 + lane]);
    red[wid][lane] = acc;
    __syncthreads();
    if (wid == 0) {
        float v = red[0][lane] + red[1][lane] + red[2][lane] + red[3][lane];
        pooled[(size_t)g * 64 + lane] = v / fmaxf((float)c, 1.f);
    }
}

// ---------------- MLP head ----------------
__global__ __launch_bounds__(256) void head_kernel(const float* __restrict__ pooled,
                                                   const float* __restrict__ dw1,
                                                   const float* __restrict__ db1,
                                                   const float* __restrict__ dw2,
                                                   const float* __restrict__ db2,
                                                   const float* __restrict__ dw3,
                                                   const float* __restrict__ db3,
                                                   float* __restrict__ out, int G) {
    int g = blockIdx.x * blockDim.x + threadIdx.x;
    if (g >= G) return;

    float m[64];
#pragma unroll
    for (int k = 0; k < 64; ++k) m[k] = pooled[(size_t)g * 64 + k];

    float h1[16];
#pragma unroll
    for (int j = 0; j < 16; ++j) h1[j] = db1[j];
    for (int k = 0; k < 64; ++k) {
        float mv = m[k];
#pragma unroll
        for (int j = 0; j < 16; ++j) h1[j] += mv * dw1[k * 16 + j];
    }
#pragma unroll
    for (int j = 0; j < 16; ++j) h1[j] = fmaxf(h1[j], 0.f);

    float h2[8];
#pragma unroll
    for (int j = 0; j < 8; ++j) h2[j] = db2[j];
#pragma unroll
    for (int k = 0; k < 16; ++k) {
        float hv = h1[k];
#pragma unroll
        for (int j = 0; j < 8; ++j) h2[j] += hv * dw2[k * 8 + j];
    }
#pragma unroll
    for (int j = 0; j < 8; ++j) h2[j] = fmaxf(h2[j], 0.f);

    float z = db3[0];
#pragma unroll
    for (int k = 0; k < 8; ++k) z += h2[k] * dw3[k];
    out[g] = 1.0f / (1.0f + expf(-z));
}

extern "C" void kernel_launch(void* const* d_in, const int* in_sizes, int n_in,
                              void* d_out, int out_size, void* d_ws, size_t ws_size,
                              hipStream_t stream) {
    const float* feat = (const float*)d_in[0];
    const int* eidx   = (const int*)d_in[1];
    const int* batch  = (const int*)d_in[2];
    const float* w1 = (const float*)d_in[3];
    const float* b1 = (const float*)d_in[4];
    const float* w2 = (const float*)d_in[5];
    const float* b2 = (const float*)d_in[6];
    const float* w3 = (const float*)d_in[7];
    const float* b3 = (const float*)d_in[8];
    const float* dw1 = (const float*)d_in[9];
    const float* db1 = (const float*)d_in[10];
    const float* dw2 = (const float*)d_in[11];
    const float* db2 = (const float*)d_in[12];
    const float* dw3 = (const float*)d_in[13];
    const float* db3 = (const float*)d_in[14];

    const int H = in_sizes[4];              // 64
    const int F = in_sizes[3] / H;          // 128
    const int Nn = in_sizes[0] / F;         // 100000
    const int E = in_sizes[1] / 2;          // 800000
    const int G = out_size;                 // 512

    const int* rows = eidx;
    const int* cols = eidx + E;

    // workspace layout (bf16 node tensors)
    unsigned short* supp = (unsigned short*)d_ws;        // bf16 support [N,64]
    unsigned short* xb = supp + (size_t)Nn * H;          // bf16 x [N,64]
    float* pooled = (float*)(xb + (size_t)Nn * H);       // [G,64]
    int* deg = (int*)(pooled + (size_t)G * H);
    int* offsets = deg + Nn;
    int* fillPos = offsets + Nn;
    int* csrSrc = fillPos + Nn;
    int* blockSums = csrSrc + E;
    int* blockOffs = blockSums + 256;
    int* gstart = blockOffs + 256;
    int* gcnt = gstart + G;

    dim3 blk(256);
    const int gemmGrid = divUp(Nn, 64);
    const int aggGrid = divUp(Nn, 4);
    const int nb = divUp(Nn, 1024);

    // ---- CSR build (XCD-partitioned) + graph bounds ----
    hipMemsetAsync(deg, 0, (size_t)Nn * sizeof(int), stream);
    hist_part<<<2048, blk, 0, stream>>>(rows, deg, E, Nn);
    scanA<<<nb, blk, 0, stream>>>(deg, offsets, blockSums, Nn);
    scanB<<<1, 64, 0, stream>>>(blockSums, blockOffs, nb);
    scanC<<<nb, blk, 0, stream>>>(offsets, blockOffs, fillPos, Nn);
    fill_part<<<2048, blk, 0, stream>>>(rows, cols, fillPos, csrSrc, E, Nn);
    graph_bounds<<<divUp(G, 256), blk, 0, stream>>>(batch, Nn, gstart, gcnt, G);

    // ---- layer 1 (K=128, A fp32) ----
    mfma_gemm<128, true><<<gemmGrid, blk, 0, stream>>>(feat, w1, supp, Nn);
    agg_csr_b<<<aggGrid, blk, 0, stream>>>(supp, offsets, deg, csrSrc, b1, xb, Nn, 1);
    // ---- layer 2 (K=64, A bf16) ----
    mfma_gemm<64, false><<<gemmGrid, blk, 0, stream>>>(xb, w2, supp, Nn);
    agg_csr_b<<<aggGrid, blk, 0, stream>>>(supp, offsets, deg, csrSrc, b2, xb, Nn, 1);
    // ---- layer 3 (K=64, A bf16) ----
    mfma_gemm<64, false><<<gemmGrid, blk, 0, stream>>>(xb, w3, supp, Nn);
    agg_csr_b<<<aggGrid, blk, 0, stream>>>(supp, offsets, deg, csrSrc, b3, xb, Nn, 0);

    // ---- segmented mean pool ----
    pool_seg_b<<<G, blk, 0, stream>>>(xb, gstart, gcnt, pooled);

    // ---- head ----
    head_kernel<<<divUp(G, 256), blk, 0, stream>>>(pooled, dw1, db1, dw2, db2,
                                                   dw3, db3, (float*)d_out, G);
}

// Round 7
// 259.737 us; speedup vs baseline: 3.0674x; 1.1398x over previous
//
#include <hip/hip_runtime.h>
#include <hip/hip_bf16.h>

// GCN: 3x (LDS-free MFMA bf16 GEMM -> subgroup CSR-gather agg -> bf16 x)
//      -> segmented mean-pool -> MLP head
// CSR built per launch with XCD-partitioned scatter. batch[] sorted.

static inline int divUp(int a, int b) { return (a + b - 1) / b; }

#define NXCD 8

using short8 = __attribute__((ext_vector_type(8))) short;
using f32x4 = __attribute__((ext_vector_type(4))) float;

__device__ __forceinline__ float bf16_to_f(unsigned short h) {
    unsigned int u = ((unsigned int)h) << 16;
    return __builtin_bit_cast(float, u);
}
__device__ __forceinline__ unsigned short f_to_bf16(float f) {
    unsigned int u = __builtin_bit_cast(unsigned int, f);
    unsigned int r = (u + 0x7FFFu + ((u >> 16) & 1u)) >> 16;  // RNE
    return (unsigned short)r;
}

// ---------------- W -> W^T bf16 (one small kernel, 3 blocks) ----------------
__global__ __launch_bounds__(256) void wconv(const float* __restrict__ w1,
                                             const float* __restrict__ w2,
                                             const float* __restrict__ w3,
                                             unsigned short* __restrict__ wt1,
                                             unsigned short* __restrict__ wt2,
                                             unsigned short* __restrict__ wt3) {
    const float* W = (blockIdx.x == 0) ? w1 : (blockIdx.x == 1 ? w2 : w3);
    unsigned short* Wt = (blockIdx.x == 0) ? wt1 : (blockIdx.x == 1 ? wt2 : wt3);
    const int K = (blockIdx.x == 0) ? 128 : 64;
    for (int m = threadIdx.x; m < 64 * K; m += 256) {
        int k = m >> 6, c = m & 63;           // W[k][c], coalesced read
        Wt[c * K + k] = f_to_bf16(W[m]);      // scattered 2B write (tiny, L2)
    }
}

// ---------------- LDS-free MFMA GEMM: out_bf16[N,64] = X[N,K] @ Wt^T ----------------
// 256 thr = 4 waves; wave w computes rows m0+w*16..+15 x 64 cols.
// A-frag & B-frag loaded directly from global (A rows stream; Wt is L2-resident).
template <int K, bool AFP32>
__global__ __launch_bounds__(256) void mfma_gemm(const void* __restrict__ Xv,
                                                 const unsigned short* __restrict__ Wt,
                                                 unsigned short* __restrict__ out,
                                                 int Nrows) {
    __shared__ unsigned short Cl[64 * 72];

    const int tid = threadIdx.x;
    const int m0 = blockIdx.x * 64;
    const int lane = tid & 63;
    const int w = tid >> 6;
    const int g = lane >> 4;       // k-chunk selector within 32-k window
    const int sl = lane & 15;
    const int r0 = w * 16;
    const int ar = m0 + r0 + sl;   // A row for this lane
    const bool aok = ar < Nrows;

    f32x4 acc[4];
#pragma unroll
    for (int cf = 0; cf < 4; ++cf) acc[cf] = (f32x4){0.f, 0.f, 0.f, 0.f};

#pragma unroll
    for (int ks = 0; ks < K / 32; ++ks) {
        const int ck = ks * 4 + g;           // 8-elem k-chunk index
        short8 a = (short8){0, 0, 0, 0, 0, 0, 0, 0};
        if (AFP32) {
            if (aok) {
                const float* p = (const float*)Xv + (size_t)ar * K + ck * 8;
                float4 x0 = *(const float4*)p;
                float4 x1 = *(const float4*)(p + 4);
                a[0] = (short)f_to_bf16(x0.x); a[1] = (short)f_to_bf16(x0.y);
                a[2] = (short)f_to_bf16(x0.z); a[3] = (short)f_to_bf16(x0.w);
                a[4] = (short)f_to_bf16(x1.x); a[5] = (short)f_to_bf16(x1.y);
                a[6] = (short)f_to_bf16(x1.z); a[7] = (short)f_to_bf16(x1.w);
            }
        } else {
            if (aok)
                a = *(const short8*)((const unsigned short*)Xv + (size_t)ar * K + ck * 8);
        }
#pragma unroll
        for (int cf = 0; cf < 4; ++cf) {
            const int bc = cf * 16 + sl;     // B col for this lane
            short8 b = *(const short8*)(Wt + (size_t)bc * K + ck * 8);
            acc[cf] = __builtin_amdgcn_mfma_f32_16x16x32_bf16(a, b, acc[cf], 0, 0, 0);
        }
    }

    // epilogue via LDS for coalesced uint4 stores
#pragma unroll
    for (int cf = 0; cf < 4; ++cf)
#pragma unroll
        for (int rg = 0; rg < 4; ++rg) {
            int row = r0 + g * 4 + rg;       // C/D: row=(lane>>4)*4+reg, col=lane&15
            Cl[row * 72 + cf * 16 + sl] = f_to_bf16(acc[cf][rg]);
        }
    __syncthreads();
    {
        int row = tid >> 2;
        int c0 = (tid & 3) * 16;
        int grow = m0 + row;
        if (grow < Nrows) {
            uint4 a = *(const uint4*)(Cl + row * 72 + c0);
            uint4 b = *(const uint4*)(Cl + row * 72 + c0 + 8);
            *(uint4*)(out + (size_t)grow * 64 + c0) = a;
            *(uint4*)(out + (size_t)grow * 64 + c0 + 8) = b;
        }
    }
}

// ---------------- CSR build (XCD-partitioned scatters) ----------------
__global__ __launch_bounds__(256) void hist_part(const int* __restrict__ rows,
                                                 int* __restrict__ deg, int E, int Nn) {
    const int p = blockIdx.x & (NXCD - 1);
    const int lo = (int)((long)p * Nn / NXCD);
    const int hi = (int)((long)(p + 1) * Nn / NXCD);
    const int nb = gridDim.x >> 3;
    const int cb = blockIdx.x >> 3;
    const int stride4 = nb * blockDim.x * 4;
    for (int i0 = (cb * blockDim.x + threadIdx.x) * 4; i0 < E; i0 += stride4) {
        if (i0 + 3 < E) {
            int4 r = *(const int4*)(rows + i0);
            if (r.x >= lo && r.x < hi) atomicAdd(&deg[r.x], 1);
            if (r.y >= lo && r.y < hi) atomicAdd(&deg[r.y], 1);
            if (r.z >= lo && r.z < hi) atomicAdd(&deg[r.z], 1);
            if (r.w >= lo && r.w < hi) atomicAdd(&deg[r.w], 1);
        } else {
            for (int j = i0; j < E; ++j) {
                int r = rows[j];
                if (r >= lo && r < hi) atomicAdd(&deg[r], 1);
            }
        }
    }
}

__global__ __launch_bounds__(256) void fill_part(const int* __restrict__ rows,
                                                 const int* __restrict__ cols,
                                                 int* __restrict__ fillPos,
                                                 int* __restrict__ csrSrc, int E, int Nn) {
    const int p = blockIdx.x & (NXCD - 1);
    const int lo = (int)((long)p * Nn / NXCD);
    const int hi = (int)((long)(p + 1) * Nn / NXCD);
    const int nb = gridDim.x >> 3;
    const int cb = blockIdx.x >> 3;
    const int stride4 = nb * blockDim.x * 4;
    for (int i0 = (cb * blockDim.x + threadIdx.x) * 4; i0 < E; i0 += stride4) {
        if (i0 + 3 < E) {
            int4 r = *(const int4*)(rows + i0);
            int4 c = *(const int4*)(cols + i0);
            if (r.x >= lo && r.x < hi) { int q = atomicAdd(&fillPos[r.x], 1); csrSrc[q] = c.x; }
            if (r.y >= lo && r.y < hi) { int q = atomicAdd(&fillPos[r.y], 1); csrSrc[q] = c.y; }
            if (r.z >= lo && r.z < hi) { int q = atomicAdd(&fillPos[r.z], 1); csrSrc[q] = c.z; }
            if (r.w >= lo && r.w < hi) { int q = atomicAdd(&fillPos[r.w], 1); csrSrc[q] = c.w; }
        } else {
            for (int j = i0; j < E; ++j) {
                int r = rows[j];
                if (r >= lo && r < hi) { int q = atomicAdd(&fillPos[r], 1); csrSrc[q] = cols[j]; }
            }
        }
    }
}

__global__ __launch_bounds__(256) void scanA(const int* __restrict__ deg,
                                             int* __restrict__ offsets,
                                             int* __restrict__ blockSums, int Nn) {
    __shared__ int wsum[4];
    const int tid = threadIdx.x;
    const int lane = tid & 63;
    const int wid = tid >> 6;
    const int i0 = blockIdx.x * 1024 + tid * 4;

    int v[4];
#pragma unroll
    for (int j = 0; j < 4; ++j) v[j] = (i0 + j < Nn) ? deg[i0 + j] : 0;
    int t = v[0] + v[1] + v[2] + v[3];

    int x = t;
#pragma unroll
    for (int d = 1; d < 64; d <<= 1) {
        int y = __shfl_up(x, d, 64);
        if (lane >= d) x += y;
    }
    if (lane == 63) wsum[wid] = x;
    __syncthreads();
    int waveExcl = 0;
#pragma unroll
    for (int w = 0; w < 4; ++w)
        if (w < wid) waveExcl += wsum[w];

    int e = waveExcl + (x - t);
#pragma unroll
    for (int j = 0; j < 4; ++j) {
        if (i0 + j < Nn) offsets[i0 + j] = e;
        e += v[j];
    }
    if (tid == 0) blockSums[blockIdx.x] = wsum[0] + wsum[1] + wsum[2] + wsum[3];
}

__global__ void scanB(int* __restrict__ blockSums, int* __restrict__ blockOffs, int nb) {
    if (threadIdx.x == 0 && blockIdx.x == 0) {
        int run = 0;
        for (int b = 0; b < nb; ++b) {
            blockOffs[b] = run;
            run += blockSums[b];
        }
    }
}

__global__ __launch_bounds__(256) void scanC(int* __restrict__ offsets,
                                             const int* __restrict__ blockOffs,
                                             int* __restrict__ fillPos, int Nn) {
    const int i0 = blockIdx.x * 1024 + threadIdx.x * 4;
    const int add = blockOffs[blockIdx.x];
#pragma unroll
    for (int j = 0; j < 4; ++j) {
        if (i0 + j < Nn) {
            int o = offsets[i0 + j] + add;
            offsets[i0 + j] = o;
            fillPos[i0 + j] = o;
        }
    }
}

// ---------------- CSR aggregation: one 16-lane subgroup per node ----------------
// 16 nodes/block. Subgroup reads its node's rows serially, 4-deep unrolled
// (16 rows in flight per wave). No cross-lane reduction needed.
__global__ __launch_bounds__(256) void agg_sg(const unsigned short* __restrict__ support,
                                              const int* __restrict__ offsets,
                                              const int* __restrict__ deg,
                                              const int* __restrict__ csrSrc,
                                              const float* __restrict__ bias,
                                              unsigned short* __restrict__ out,
                                              int Nn, int doRelu) {
    const int tid = threadIdx.x;
    const int sl = tid & 15;
    const int node = blockIdx.x * 16 + (tid >> 4);
    if (node >= Nn) return;
    const int off = offsets[node];
    const int d = deg[node];
    const int d16 = d < 16 ? d : 16;
    const int laneBase = (tid & 63) & ~15;

    int idx = (sl < d16) ? csrSrc[off + sl] : 0;  // coalesced index preload

    float4 a0 = make_float4(0.f, 0.f, 0.f, 0.f);
    float4 a1 = make_float4(0.f, 0.f, 0.f, 0.f);
    float4 a2 = make_float4(0.f, 0.f, 0.f, 0.f);
    float4 a3 = make_float4(0.f, 0.f, 0.f, 0.f);
    int i = 0;
    for (; i + 3 < d16; i += 4) {
        int s0 = __shfl(idx, laneBase + i);
        int s1 = __shfl(idx, laneBase + i + 1);
        int s2 = __shfl(idx, laneBase + i + 2);
        int s3 = __shfl(idx, laneBase + i + 3);
        ushort4 v0 = *(const ushort4*)(support + (size_t)s0 * 64 + sl * 4);
        ushort4 v1 = *(const ushort4*)(support + (size_t)s1 * 64 + sl * 4);
        ushort4 v2 = *(const ushort4*)(support + (size_t)s2 * 64 + sl * 4);
        ushort4 v3 = *(const ushort4*)(support + (size_t)s3 * 64 + sl * 4);
        a0.x += bf16_to_f(v0.x); a0.y += bf16_to_f(v0.y);
        a0.z += bf16_to_f(v0.z); a0.w += bf16_to_f(v0.w);
        a1.x += bf16_to_f(v1.x); a1.y += bf16_to_f(v1.y);
        a1.z += bf16_to_f(v1.z); a1.w += bf16_to_f(v1.w);
        a2.x += bf16_to_f(v2.x); a2.y += bf16_to_f(v2.y);
        a2.z += bf16_to_f(v2.z); a2.w += bf16_to_f(v2.w);
        a3.x += bf16_to_f(v3.x); a3.y += bf16_to_f(v3.y);
        a3.z += bf16_to_f(v3.z); a3.w += bf16_to_f(v3.w);
    }
    for (; i < d16; ++i) {
        int s = __shfl(idx, laneBase + i);
        ushort4 v = *(const ushort4*)(support + (size_t)s * 64 + sl * 4);
        a0.x += bf16_to_f(v.x); a0.y += bf16_to_f(v.y);
        a0.z += bf16_to_f(v.z); a0.w += bf16_to_f(v.w);
    }
    for (int j = 16; j < d; ++j) {  // rare: degree > 16
        int s = csrSrc[off + j];
        ushort4 v = *(const ushort4*)(support + (size_t)s * 64 + sl * 4);
        a0.x += bf16_to_f(v.x); a0.y += bf16_to_f(v.y);
        a0.z += bf16_to_f(v.z); a0.w += bf16_to_f(v.w);
    }

    float4 b4 = *(const float4*)(bias + sl * 4);
    float ox = ((a0.x + a1.x) + (a2.x + a3.x)) + b4.x;
    float oy = ((a0.y + a1.y) + (a2.y + a3.y)) + b4.y;
    float oz = ((a0.z + a1.z) + (a2.z + a3.z)) + b4.z;
    float ow = ((a0.w + a1.w) + (a2.w + a3.w)) + b4.w;
    if (doRelu) {
        ox = fmaxf(ox, 0.f); oy = fmaxf(oy, 0.f);
        oz = fmaxf(oz, 0.f); ow = fmaxf(ow, 0.f);
    }
    ushort4 o;
    o.x = f_to_bf16(ox); o.y = f_to_bf16(oy);
    o.z = f_to_bf16(oz); o.w = f_to_bf16(ow);
    *(ushort4*)(out + (size_t)node * 64 + sl * 4) = o;
}

// ---------------- graph bounds via binary search on sorted batch ----------------
__global__ __launch_bounds__(256) void graph_bounds(const int* __restrict__ batch,
                                                    int Nn, int* __restrict__ gstart,
                                                    int* __restrict__ gcnt, int G) {
    int g = blockIdx.x * blockDim.x + threadIdx.x;
    if (g >= G) return;
    int lo = 0, hi = Nn;
    while (lo < hi) { int mid = (lo + hi) >> 1; if (batch[mid] < g) lo = mid + 1; else hi = mid; }
    int s = lo;
    hi = Nn;
    while (lo < hi) { int mid = (lo + hi) >> 1; if (batch[mid] < g + 1) lo = mid + 1; else hi = mid; }
    gstart[g] = s;
    gcnt[g] = lo - s;
}

// ---------------- segmented mean pool (bf16 x): one block per graph ----------------
__global__ __launch_bounds__(256) void pool_seg_b(const unsigned short* __restrict__ x,
                                                  const int* __restrict__ gstart,
                                                  const int* __restrict__ gcnt,
                                                  float* __restrict__ pooled) {
    __shared__ float red[4][64];
    const int g = blockIdx.x;
    const int lane = threadIdx.x & 63;
    const int wid = threadIdx.x >> 6;
    const int s = gstart[g];
    const int c = gcnt[g];

    float acc = 0.f;
    for (int i = s + wid; i < s + c; i += 4)
        acc += bf16_to_f(x[(size_t)i * 64 + lane]);
    red[wid][lane] = acc;
    __syncthreads();
    if (wid == 0) {
        float v = red[0][lane] + red[1][lane] + red[2][lane] + red[3][lane];
        pooled[(size_t)g * 64 + lane] = v / fmaxf((float)c, 1.f);
    }
}

// ---------------- MLP head ----------------
__global__ __launch_bounds__(256) void head_kernel(const float* __restrict__ pooled,
                                                   const float* __restrict__ dw1,
                                                   const float* __restrict__ db1,
                                                   const float* __restrict__ dw2,
                                                   const float* __restrict__ db2,
                                                   const float* __restrict__ dw3,
                                                   const float* __restrict__ db3,
                                                   float* __restrict__ out, int G) {
    int g = blockIdx.x * blockDim.x + threadIdx.x;
    if (g >= G) return;

    float m[64];
#pragma unroll
    for (int k = 0; k < 64; ++k) m[k] = pooled[(size_t)g * 64 + k];

    float h1[16];
#pragma unroll
    for (int j = 0; j < 16; ++j) h1[j] = db1[j];
    for (int k = 0; k < 64; ++k) {
        float mv = m[k];
#pragma unroll
        for (int j = 0; j < 16; ++j) h1[j] += mv * dw1[k * 16 + j];
    }
#pragma unroll
    for (int j = 0; j < 16; ++j) h1[j] = fmaxf(h1[j], 0.f);

    float h2[8];
#pragma unroll
    for (int j = 0; j < 8; ++j) h2[j] = db2[j];
#pragma unroll
    for (int k = 0; k < 16; ++k) {
        float hv = h1[k];
#pragma unroll
        for (int j = 0; j < 8; ++j) h2[j] += hv * dw2[k * 8 + j];
    }
#pragma unroll
    for (int j = 0; j < 8; ++j) h2[j] = fmaxf(h2[j], 0.f);

    float z = db3[0];
#pragma unroll
    for (int k = 0; k < 8; ++k) z += h2[k] * dw3[k];
    out[g] = 1.0f / (1.0f + expf(-z));
}

extern "C" void kernel_launch(void* const* d_in, const int* in_sizes, int n_in,
                              void* d_out, int out_size, void* d_ws, size_t ws_size,
                              hipStream_t stream) {
    const float* feat = (const float*)d_in[0];
    const int* eidx   = (const int*)d_in[1];
    const int* batch  = (const int*)d_in[2];
    const float* w1 = (const float*)d_in[3];
    const float* b1 = (const float*)d_in[4];
    const float* w2 = (const float*)d_in[5];
    const float* b2 = (const float*)d_in[6];
    const float* w3 = (const float*)d_in[7];
    const float* b3 = (const float*)d_in[8];
    const float* dw1 = (const float*)d_in[9];
    const float* db1 = (const float*)d_in[10];
    const float* dw2 = (const float*)d_in[11];
    const float* db2 = (const float*)d_in[12];
    const float* dw3 = (const float*)d_in[13];
    const float* db3 = (const float*)d_in[14];

    const int H = in_sizes[4];              // 64
    const int F = in_sizes[3] / H;          // 128
    const int Nn = in_sizes[0] / F;         // 100000
    const int E = in_sizes[1] / 2;          // 800000
    const int G = out_size;                 // 512

    const int* rows = eidx;
    const int* cols = eidx + E;

    // workspace layout
    unsigned short* supp = (unsigned short*)d_ws;        // bf16 support [N,64]
    unsigned short* xb = supp + (size_t)Nn * H;          // bf16 x [N,64]
    unsigned short* wt1 = xb + (size_t)Nn * H;           // bf16 W1^T [64][128]
    unsigned short* wt2 = wt1 + 64 * 128;                // bf16 W2^T [64][64]
    unsigned short* wt3 = wt2 + 64 * 64;                 // bf16 W3^T [64][64]
    float* pooled = (float*)(wt3 + 64 * 64);             // [G,64]
    int* deg = (int*)(pooled + (size_t)G * H);
    int* offsets = deg + Nn;
    int* fillPos = offsets + Nn;
    int* csrSrc = fillPos + Nn;
    int* blockSums = csrSrc + E;
    int* blockOffs = blockSums + 256;
    int* gstart = blockOffs + 256;
    int* gcnt = gstart + G;

    dim3 blk(256);
    const int gemmGrid = divUp(Nn, 64);
    const int aggGrid = divUp(Nn, 16);
    const int nb = divUp(Nn, 1024);

    // ---- CSR build (XCD-partitioned) + W conversion + graph bounds ----
    hipMemsetAsync(deg, 0, (size_t)Nn * sizeof(int), stream);
    wconv<<<3, blk, 0, stream>>>(w1, w2, w3, wt1, wt2, wt3);
    hist_part<<<2048, blk, 0, stream>>>(rows, deg, E, Nn);
    scanA<<<nb, blk, 0, stream>>>(deg, offsets, blockSums, Nn);
    scanB<<<1, 64, 0, stream>>>(blockSums, blockOffs, nb);
    scanC<<<nb, blk, 0, stream>>>(offsets, blockOffs, fillPos, Nn);
    fill_part<<<2048, blk, 0, stream>>>(rows, cols, fillPos, csrSrc, E, Nn);
    graph_bounds<<<divUp(G, 256), blk, 0, stream>>>(batch, Nn, gstart, gcnt, G);

    // ---- layer 1 (K=128, A fp32) ----
    mfma_gemm<128, true><<<gemmGrid, blk, 0, stream>>>(feat, wt1, supp, Nn);
    agg_sg<<<aggGrid, blk, 0, stream>>>(supp, offsets, deg, csrSrc, b1, xb, Nn, 1);
    // ---- layer 2 (K=64, A bf16) ----
    mfma_gemm<64, false><<<gemmGrid, blk, 0, stream>>>(xb, wt2, supp, Nn);
    agg_sg<<<aggGrid, blk, 0, stream>>>(supp, offsets, deg, csrSrc, b2, xb, Nn, 1);
    // ---- layer 3 (K=64, A bf16) ----
    mfma_gemm<64, false><<<gemmGrid, blk, 0, stream>>>(xb, wt3, supp, Nn);
    agg_sg<<<aggGrid, blk, 0, stream>>>(supp, offsets, deg, csrSrc, b3, xb, Nn, 0);

    // ---- segmented mean pool ----
    pool_seg_b<<<G, blk, 0, stream>>>(xb, gstart, gcnt, pooled);

    // ---- head ----
    head_kernel<<<divUp(G, 256), blk, 0, stream>>>(pooled, dw1, db1, dw2, db2,
                                                   dw3, db3, (float*)d_out, G);
}